// Round 1
// baseline (340.554 us; speedup 1.0000x reference)
//
#include <hip/hip_runtime.h>
#include <hip/hip_bf16.h>

typedef unsigned short u16;
typedef unsigned int u32;
typedef u16 u16x8 __attribute__((ext_vector_type(8)));
typedef u16 u16x4 __attribute__((ext_vector_type(4)));
typedef short bfx8 __attribute__((ext_vector_type(8)));
typedef float f32x4 __attribute__((ext_vector_type(4)));

#define AS1 __attribute__((address_space(1)))
#define AS3 __attribute__((address_space(3)))

__device__ __forceinline__ u16 f2bf(float f) {
  union { float f; u32 u; } c; c.f = f;
  u32 u = c.u;
  u += 0x7fffu + ((u >> 16) & 1u);
  return (u16)(u >> 16);
}

// ---------------- weight fp32 -> bf16 ----------------
__global__ __launch_bounds__(256) void cvt_bf16_kernel(const float* __restrict__ s,
                                                       u16* __restrict__ d, int n4) {
  int i = blockIdx.x * 256 + threadIdx.x;
  if (i >= n4) return;
  float4 v = ((const float4*)s)[i];
  u16x4 o;
  o[0] = f2bf(v.x); o[1] = f2bf(v.y); o[2] = f2bf(v.z); o[3] = f2bf(v.w);
  ((u16x4*)d)[i] = o;
}

// ---------------- LayerNorm (D=512), fp32 in -> bf16 out ----------------
__global__ __launch_bounds__(256) void ln_kernel(const float* __restrict__ x,
                                                 const float* __restrict__ g,
                                                 const float* __restrict__ be,
                                                 u16* __restrict__ out, int ntok) {
  int gw = (blockIdx.x * 256 + threadIdx.x) >> 6;
  int lane = threadIdx.x & 63;
  if (gw >= ntok) return;
  const float4* row = (const float4*)(x + (size_t)gw * 512);
  float4 a = row[2 * lane], b = row[2 * lane + 1];
  float s = a.x + a.y + a.z + a.w + b.x + b.y + b.z + b.w;
  float q = a.x*a.x + a.y*a.y + a.z*a.z + a.w*a.w + b.x*b.x + b.y*b.y + b.z*b.z + b.w*b.w;
#pragma unroll
  for (int m = 1; m < 64; m <<= 1) { s += __shfl_xor(s, m); q += __shfl_xor(q, m); }
  float mean = s * (1.f / 512.f);
  float var = q * (1.f / 512.f) - mean * mean;
  float rs = rsqrtf(var + 1e-5f);
  const float4* g4 = (const float4*)g;
  const float4* b4 = (const float4*)be;
  float4 ga = g4[2 * lane], gb = g4[2 * lane + 1];
  float4 ba = b4[2 * lane], bb = b4[2 * lane + 1];
  u16x8 o;
  o[0] = f2bf((a.x - mean) * rs * ga.x + ba.x);
  o[1] = f2bf((a.y - mean) * rs * ga.y + ba.y);
  o[2] = f2bf((a.z - mean) * rs * ga.z + ba.z);
  o[3] = f2bf((a.w - mean) * rs * ga.w + ba.w);
  o[4] = f2bf((b.x - mean) * rs * gb.x + bb.x);
  o[5] = f2bf((b.y - mean) * rs * gb.y + bb.y);
  o[6] = f2bf((b.z - mean) * rs * gb.z + bb.z);
  o[7] = f2bf((b.w - mean) * rs * gb.w + bb.w);
  ((u16x8*)(out + (size_t)gw * 512))[lane] = o;
}

// ---------------- GEMM: C(N,M) = A(N,K)bf16 @ W(M,K)bf16^T + bias ----------------
// EPI: 0 = bf16 out, 1 = bf16 out + relu, 2 = fp32 out + residual add
template <int EPI>
__global__ __launch_bounds__(256) void gemm_bt(const u16* __restrict__ A,
                                               const u16* __restrict__ Bw,
                                               const float* __restrict__ bias,
                                               const float* __restrict__ res,
                                               void* __restrict__ Cout,
                                               int N, int M, int K) {
  __shared__ __align__(16) u16 lA[128 * 64];
  __shared__ __align__(16) u16 lB[128 * 64];
  const int tid = threadIdx.x;
  const int lane = tid & 63, w = tid >> 6;
  const int wr = w >> 1, wc = w & 1;
  const int bn = blockIdx.y * 128;
  const int bm = blockIdx.x * 128;
  const int r15 = lane & 15, kg = lane >> 4;

  f32x4 acc[4][4] = {};

  const int lrw = lane >> 3, lcl = (lane & 7) * 8;

  for (int k0 = 0; k0 < K; k0 += 64) {
    const u16* gA = A + (size_t)bn * K + k0;
    const u16* gB = Bw + (size_t)bm * K + k0;
#pragma unroll
    for (int i = 0; i < 4; ++i) {
      int rbase = i * 32 + w * 8;
      __builtin_amdgcn_global_load_lds((AS1 u32*)(gA + (size_t)(rbase + lrw) * K + lcl),
                                       (AS3 u32*)&lA[rbase * 64], 16, 0, 0);
      __builtin_amdgcn_global_load_lds((AS1 u32*)(gB + (size_t)(rbase + lrw) * K + lcl),
                                       (AS3 u32*)&lB[rbase * 64], 16, 0, 0);
    }
    __syncthreads();
#pragma unroll
    for (int kk = 0; kk < 64; kk += 32) {
      bfx8 a[4], b[4];
#pragma unroll
      for (int i = 0; i < 4; ++i)
        a[i] = *(const bfx8*)&lA[(wr * 64 + i * 16 + r15) * 64 + kk + kg * 8];
#pragma unroll
      for (int j = 0; j < 4; ++j)
        b[j] = *(const bfx8*)&lB[(wc * 64 + j * 16 + r15) * 64 + kk + kg * 8];
#pragma unroll
      for (int i = 0; i < 4; ++i)
#pragma unroll
        for (int j = 0; j < 4; ++j)
          acc[i][j] = __builtin_amdgcn_mfma_f32_16x16x32_bf16(a[i], b[j], acc[i][j], 0, 0, 0);
    }
    __syncthreads();
  }

#pragma unroll
  for (int i = 0; i < 4; ++i) {
#pragma unroll
    for (int j = 0; j < 4; ++j) {
      int col = bm + wc * 64 + j * 16 + r15;
      float bv = bias[col];
#pragma unroll
      for (int r = 0; r < 4; ++r) {
        int row = bn + wr * 64 + i * 16 + kg * 4 + r;
        float v = acc[i][j][r] + bv;
        if (EPI == 1) v = fmaxf(v, 0.f);
        if (EPI == 2) {
          ((float*)Cout)[(size_t)row * M + col] = res[(size_t)row * M + col] + v;
        } else {
          ((u16*)Cout)[(size_t)row * M + col] = f2bf(v);
        }
      }
    }
  }
}

// ---------------- flash attention, head dim 64, B=8 token interleave ----------------
// token (s,b) at row s*8+b; element (s,b,h,d) at base + (s*8+b)*stride + h*64 + d
__global__ __launch_bounds__(256) void attn_kernel(const u16* __restrict__ qB,
                                                   const u16* __restrict__ kB,
                                                   const u16* __restrict__ vB,
                                                   u16* __restrict__ oB,
                                                   int qStride, int kvStride, int Sk) {
  __shared__ __align__(16) u16 lK[64 * 64];
  __shared__ __align__(16) u16 lVT[64 * 64];
  __shared__ __align__(16) u16 lP[4][16 * 64];
  const int tid = threadIdx.x, lane = tid & 63, w = tid >> 6;
  const int b = blockIdx.y, h = blockIdx.z, qt = blockIdx.x;
  const int r15 = lane & 15, kg = lane >> 4;

  const int qs = qt * 64 + w * 16 + r15;
  const u16* qrow = qB + (size_t)(qs * 8 + b) * qStride + h * 64;
  bfx8 qf0 = *(const bfx8*)(qrow + kg * 8);
  bfx8 qf1 = *(const bfx8*)(qrow + 32 + kg * 8);

  f32x4 oacc[4] = {};
  float mrow[4], lsum[4];
#pragma unroll
  for (int r = 0; r < 4; ++r) { mrow[r] = -1e30f; lsum[r] = 0.f; }

  for (int kt = 0; kt < Sk; kt += 64) {
    // stage K (row-major [kk][d]) via global_load_lds
    {
      int lrw = lane >> 3, lcl = (lane & 7) * 8;
#pragma unroll
      for (int i = 0; i < 2; ++i) {
        int rbase = i * 32 + w * 8;
        int sk = kt + rbase + lrw;
        const u16* gp = kB + (size_t)(sk * 8 + b) * kvStride + h * 64 + lcl;
        __builtin_amdgcn_global_load_lds((AS1 u32*)gp, (AS3 u32*)&lK[rbase * 64], 16, 0, 0);
      }
    }
    // stage V transposed [d][kk]
    {
      int kk = tid >> 2, d0 = (tid & 3) * 16;
      const u16* vp = vB + (size_t)((kt + kk) * 8 + b) * kvStride + h * 64 + d0;
      u16x8 v0 = *(const u16x8*)vp;
      u16x8 v1 = *(const u16x8*)(vp + 8);
#pragma unroll
      for (int e = 0; e < 8; ++e) lVT[(d0 + e) * 64 + kk] = v0[e];
#pragma unroll
      for (int e = 0; e < 8; ++e) lVT[(d0 + 8 + e) * 64 + kk] = v1[e];
    }
    __syncthreads();

    // S = Q K^T  (16 rows x 64 cols per wave)
    f32x4 sacc[4] = {};
#pragma unroll
    for (int j = 0; j < 4; ++j) {
      bfx8 kf0 = *(const bfx8*)&lK[(j * 16 + r15) * 64 + kg * 8];
      bfx8 kf1 = *(const bfx8*)&lK[(j * 16 + r15) * 64 + 32 + kg * 8];
      sacc[j] = __builtin_amdgcn_mfma_f32_16x16x32_bf16(qf0, kf0, sacc[j], 0, 0, 0);
      sacc[j] = __builtin_amdgcn_mfma_f32_16x16x32_bf16(qf1, kf1, sacc[j], 0, 0, 0);
    }
#pragma unroll
    for (int j = 0; j < 4; ++j)
#pragma unroll
      for (int r = 0; r < 4; ++r) sacc[j][r] *= 0.125f;

    // row max over 64 cols: per-lane over frags, then across 16 lanes
    float pmax[4];
#pragma unroll
    for (int r = 0; r < 4; ++r)
      pmax[r] = fmaxf(fmaxf(sacc[0][r], sacc[1][r]), fmaxf(sacc[2][r], sacc[3][r]));
#pragma unroll
    for (int m = 1; m < 16; m <<= 1)
#pragma unroll
      for (int r = 0; r < 4; ++r) pmax[r] = fmaxf(pmax[r], __shfl_xor(pmax[r], m));

    float corr[4];
#pragma unroll
    for (int r = 0; r < 4; ++r) {
      float mn = fmaxf(mrow[r], pmax[r]);
      corr[r] = __expf(mrow[r] - mn);
      mrow[r] = mn;
    }
    float p[4][4];
    float psum[4] = {0.f, 0.f, 0.f, 0.f};
#pragma unroll
    for (int j = 0; j < 4; ++j)
#pragma unroll
      for (int r = 0; r < 4; ++r) {
        float e = __expf(sacc[j][r] - mrow[r]);
        p[j][r] = e;
        psum[r] += e;
      }
#pragma unroll
    for (int m = 1; m < 16; m <<= 1)
#pragma unroll
      for (int r = 0; r < 4; ++r) psum[r] += __shfl_xor(psum[r], m);
#pragma unroll
    for (int r = 0; r < 4; ++r) lsum[r] = lsum[r] * corr[r] + psum[r];
#pragma unroll
    for (int j = 0; j < 4; ++j)
#pragma unroll
      for (int r = 0; r < 4; ++r) oacc[j][r] *= corr[r];

    // P -> bf16 -> per-wave LDS, re-fragment for PV
    u16* myP = &lP[w][0];
#pragma unroll
    for (int j = 0; j < 4; ++j)
#pragma unroll
      for (int r = 0; r < 4; ++r)
        myP[(kg * 4 + r) * 64 + j * 16 + r15] = f2bf(p[j][r]);
    __syncthreads();

    // O += P @ V
#pragma unroll
    for (int s2 = 0; s2 < 2; ++s2) {
      bfx8 pf = *(const bfx8*)&myP[r15 * 64 + s2 * 32 + kg * 8];
#pragma unroll
      for (int j = 0; j < 4; ++j) {
        bfx8 vf = *(const bfx8*)&lVT[(j * 16 + r15) * 64 + s2 * 32 + kg * 8];
        oacc[j] = __builtin_amdgcn_mfma_f32_16x16x32_bf16(pf, vf, oacc[j], 0, 0, 0);
      }
    }
    __syncthreads();
  }

  float inv[4];
#pragma unroll
  for (int r = 0; r < 4; ++r) inv[r] = 1.f / lsum[r];
#pragma unroll
  for (int j = 0; j < 4; ++j)
#pragma unroll
    for (int r = 0; r < 4; ++r) {
      int s = qt * 64 + w * 16 + kg * 4 + r;
      oB[(size_t)(s * 8 + b) * 512 + h * 64 + j * 16 + r15] = f2bf(oacc[j][r] * inv[r]);
    }
}

extern "C" void kernel_launch(void* const* d_in, const int* in_sizes, int n_in,
                              void* d_out, int out_size, void* d_ws, size_t ws_size,
                              hipStream_t stream) {
  const float* rna    = (const float*)d_in[0];
  const float* prot   = (const float*)d_in[1];
  const float* Wqkv_s = (const float*)d_in[2];
  const float* bqkv_s = (const float*)d_in[3];
  const float* Wo_s   = (const float*)d_in[4];
  const float* bo_s   = (const float*)d_in[5];
  const float* Wqkv_c = (const float*)d_in[6];
  const float* bqkv_c = (const float*)d_in[7];
  const float* Wo_c   = (const float*)d_in[8];
  const float* bo_c   = (const float*)d_in[9];
  const float* W1     = (const float*)d_in[10];
  const float* b1     = (const float*)d_in[11];
  const float* W2     = (const float*)d_in[12];
  const float* b2     = (const float*)d_in[13];
  const float* g0  = (const float*)d_in[14];
  const float* be0 = (const float*)d_in[15];
  const float* g11 = (const float*)d_in[16];
  const float* be11= (const float*)d_in[17];
  const float* g12 = (const float*)d_in[18];
  const float* be12= (const float*)d_in[19];
  const float* g2  = (const float*)d_in[20];
  const float* be2 = (const float*)d_in[21];
  float* out = (float*)d_out;

  u16* wbf      = (u16*)d_ws;
  u16* w_qkv_s  = wbf;
  u16* w_o_s    = wbf + 786432;
  u16* w_qkv_c  = wbf + 1048576;
  u16* w_o_c    = wbf + 1835008;
  u16* w_1      = wbf + 2097152;
  u16* w_2      = wbf + 3145728;
  u16* hbuf     = wbf + 4194304;            // 8192x512 bf16
  u16* qkv      = hbuf + 4194304;           // up to 8192x1536 bf16
  u16* kvc      = qkv + 8192 * 512;         // cross K|V 4096x1024
  u16* attnO    = qkv + 12582912;           // 8192x512 bf16
  u16* hp       = attnO + 4194304;          // 4096x512 bf16
  u16* ffnmid   = qkv;                      // 8192x2048 bf16 (reuses qkv+attnO)

  cvt_bf16_kernel<<<768,  256, 0, stream>>>(Wqkv_s, w_qkv_s, 196608);
  cvt_bf16_kernel<<<256,  256, 0, stream>>>(Wo_s,   w_o_s,    65536);
  cvt_bf16_kernel<<<768,  256, 0, stream>>>(Wqkv_c, w_qkv_c, 196608);
  cvt_bf16_kernel<<<256,  256, 0, stream>>>(Wo_c,   w_o_c,    65536);
  cvt_bf16_kernel<<<1024, 256, 0, stream>>>(W1,     w_1,     262144);
  cvt_bf16_kernel<<<1024, 256, 0, stream>>>(W2,     w_2,     262144);

  // self-attention block
  ln_kernel<<<2048, 256, 0, stream>>>(rna, g0, be0, hbuf, 8192);
  gemm_bt<0><<<dim3(12, 64), 256, 0, stream>>>(hbuf, w_qkv_s, bqkv_s, nullptr, qkv, 8192, 1536, 512);
  attn_kernel<<<dim3(16, 8, 8), 256, 0, stream>>>(qkv, qkv + 512, qkv + 1024, attnO, 1536, 1536, 1024);
  gemm_bt<2><<<dim3(4, 64), 256, 0, stream>>>(attnO, w_o_s, bo_s, rna, out, 8192, 512, 512);

  // cross-attention block
  ln_kernel<<<2048, 256, 0, stream>>>(out, g11, be11, hbuf, 8192);
  ln_kernel<<<1024, 256, 0, stream>>>(prot, g12, be12, hp, 4096);
  gemm_bt<0><<<dim3(4, 64), 256, 0, stream>>>(hbuf, w_qkv_c, bqkv_c, nullptr, qkv, 8192, 512, 512);
  gemm_bt<0><<<dim3(8, 32), 256, 0, stream>>>(hp, w_qkv_c + 512 * 512, bqkv_c + 512, nullptr, kvc, 4096, 1024, 512);
  attn_kernel<<<dim3(16, 8, 8), 256, 0, stream>>>(qkv, kvc, kvc + 512, attnO, 512, 1024, 512);
  gemm_bt<2><<<dim3(4, 64), 256, 0, stream>>>(attnO, w_o_c, bo_c, out, out, 8192, 512, 512);

  // FFN block
  ln_kernel<<<2048, 256, 0, stream>>>(out, g2, be2, hbuf, 8192);
  gemm_bt<1><<<dim3(16, 64), 256, 0, stream>>>(hbuf, w_1, b1, nullptr, ffnmid, 8192, 2048, 512);
  gemm_bt<2><<<dim3(4, 64), 256, 0, stream>>>(ffnmid, w_2, b2, out, out, 8192, 512, 2048);
}

// Round 2
// 287.333 us; speedup vs baseline: 1.1852x; 1.1852x over previous
//
#include <hip/hip_runtime.h>

typedef unsigned short u16;
typedef unsigned int u32;
typedef u16 u16x8 __attribute__((ext_vector_type(8)));
typedef u16 u16x4 __attribute__((ext_vector_type(4)));
typedef short bfx8 __attribute__((ext_vector_type(8)));
typedef float f32x4 __attribute__((ext_vector_type(4)));

#define AS1 __attribute__((address_space(1)))
#define AS3 __attribute__((address_space(3)))

__device__ __forceinline__ u16 f2bf(float f) {
  union { float f; u32 u; } c; c.f = f;
  u32 u = c.u;
  u += 0x7fffu + ((u >> 16) & 1u);
  return (u16)(u >> 16);
}

// ---------------- all-weights fp32 -> bf16 (merged) ----------------
__global__ __launch_bounds__(256) void cvt6_kernel(const float* __restrict__ a0, const float* __restrict__ a1,
                                                   const float* __restrict__ a2, const float* __restrict__ a3,
                                                   const float* __restrict__ a4, const float* __restrict__ a5,
                                                   u16* __restrict__ b0, u16* __restrict__ b1,
                                                   u16* __restrict__ b2, u16* __restrict__ b3,
                                                   u16* __restrict__ b4, u16* __restrict__ b5) {
  int i = blockIdx.x * 256 + threadIdx.x;
  const float* s; u16* d; int off;
  if      (i < 196608) { s = a0; d = b0; off = i; }
  else if (i < 262144) { s = a1; d = b1; off = i - 196608; }
  else if (i < 458752) { s = a2; d = b2; off = i - 262144; }
  else if (i < 524288) { s = a3; d = b3; off = i - 458752; }
  else if (i < 786432) { s = a4; d = b4; off = i - 524288; }
  else                 { s = a5; d = b5; off = i - 786432; }
  float4 v = ((const float4*)s)[off];
  u16x4 o;
  o[0] = f2bf(v.x); o[1] = f2bf(v.y); o[2] = f2bf(v.z); o[3] = f2bf(v.w);
  ((u16x4*)d)[off] = o;
}

// ---------------- LayerNorm (D=512), fp32 in -> bf16 out ----------------
__global__ __launch_bounds__(256) void ln_kernel(const float* __restrict__ x,
                                                 const float* __restrict__ g,
                                                 const float* __restrict__ be,
                                                 u16* __restrict__ out, int ntok) {
  int gw = (blockIdx.x * 256 + threadIdx.x) >> 6;
  int lane = threadIdx.x & 63;
  if (gw >= ntok) return;
  const float4* row = (const float4*)(x + (size_t)gw * 512);
  float4 a = row[2 * lane], b = row[2 * lane + 1];
  float s = a.x + a.y + a.z + a.w + b.x + b.y + b.z + b.w;
  float q = a.x*a.x + a.y*a.y + a.z*a.z + a.w*a.w + b.x*b.x + b.y*b.y + b.z*b.z + b.w*b.w;
#pragma unroll
  for (int m = 1; m < 64; m <<= 1) { s += __shfl_xor(s, m); q += __shfl_xor(q, m); }
  float mean = s * (1.f / 512.f);
  float var = q * (1.f / 512.f) - mean * mean;
  float rs = rsqrtf(var + 1e-5f);
  const float4* g4 = (const float4*)g;
  const float4* b4 = (const float4*)be;
  float4 ga = g4[2 * lane], gb = g4[2 * lane + 1];
  float4 ba = b4[2 * lane], bb = b4[2 * lane + 1];
  u16x8 o;
  o[0] = f2bf((a.x - mean) * rs * ga.x + ba.x);
  o[1] = f2bf((a.y - mean) * rs * ga.y + ba.y);
  o[2] = f2bf((a.z - mean) * rs * ga.z + ba.z);
  o[3] = f2bf((a.w - mean) * rs * ga.w + ba.w);
  o[4] = f2bf((b.x - mean) * rs * gb.x + bb.x);
  o[5] = f2bf((b.y - mean) * rs * gb.y + bb.y);
  o[6] = f2bf((b.z - mean) * rs * gb.z + bb.z);
  o[7] = f2bf((b.w - mean) * rs * gb.w + bb.w);
  ((u16x8*)(out + (size_t)gw * 512))[lane] = o;
}

// ---------------- V transpose: V(s,b,h,d) -> Vt[(b*8+h)*64+d][s] ----------------
__global__ __launch_bounds__(256) void vt_kernel(const u16* __restrict__ vB, u16* __restrict__ vt,
                                                 int stride, int S) {
  __shared__ u16 lt[64 * 68];
  const int t = threadIdx.x;
  const int b = blockIdx.y, h = blockIdx.z;
  const int sr = t >> 3, dc = (t & 7) * 8;
#pragma unroll
  for (int p = 0; p < 2; ++p) {
    int s = blockIdx.x * 64 + sr + p * 32;
    u16x8 v = *(const u16x8*)(vB + (size_t)(s * 8 + b) * stride + h * 64 + dc);
    u16x4 lo, hi;
    lo[0]=v[0]; lo[1]=v[1]; lo[2]=v[2]; lo[3]=v[3];
    hi[0]=v[4]; hi[1]=v[5]; hi[2]=v[6]; hi[3]=v[7];
    *(u16x4*)&lt[(sr + p * 32) * 68 + dc] = lo;
    *(u16x4*)&lt[(sr + p * 32) * 68 + dc + 4] = hi;
  }
  __syncthreads();
#pragma unroll
  for (int p = 0; p < 2; ++p) {
    int d = sr + p * 32;
    u16x8 o;
#pragma unroll
    for (int e = 0; e < 8; ++e) o[e] = lt[(dc + e) * 68 + d];
    *(u16x8*)(vt + ((size_t)(b * 8 + h) * 64 + d) * S + blockIdx.x * 64 + dc) = o;
  }
}

// ---------------- GEMM: C(N,M) = A(N,K)bf16 @ W(M,K)bf16^T + bias ----------------
// EPI: 0 = bf16 out, 1 = bf16 out + relu, 2 = fp32 out + residual add
// BN: block tile cols (128 or 64); block tile rows always 128
template <int EPI, int BN>
__global__ __launch_bounds__(256) void gemm_bt(const u16* __restrict__ A,
                                               const u16* __restrict__ Bw,
                                               const float* __restrict__ bias,
                                               const float* __restrict__ res,
                                               void* __restrict__ Cout,
                                               int N, int M, int K) {
  constexpr int WC = BN / 64;      // waves along cols
  constexpr int WR = 4 / WC;       // waves along rows
  constexpr int RPW = 128 / WR;    // rows per wave
  constexpr int IM = RPW / 16;     // row frags per wave
  __shared__ __align__(16) u16 lA[128 * 64];
  __shared__ __align__(16) u16 lB[BN * 64];
  const int tid = threadIdx.x;
  const int lane = tid & 63, w = tid >> 6;
  const int wr = w / WC, wc = w % WC;
  const int bn = blockIdx.y * 128;
  const int bm = blockIdx.x * BN;
  const int r15 = lane & 15, kg = lane >> 4;

  f32x4 acc[IM][4] = {};

  const int lrw = lane >> 3, lcl = (lane & 7) * 8;

  for (int k0 = 0; k0 < K; k0 += 64) {
    const u16* gA = A + (size_t)bn * K + k0;
    const u16* gB = Bw + (size_t)bm * K + k0;
#pragma unroll
    for (int i = 0; i < 4; ++i) {
      int rbase = i * 32 + w * 8;
      __builtin_amdgcn_global_load_lds((AS1 u32*)(gA + (size_t)(rbase + lrw) * K + lcl),
                                       (AS3 u32*)&lA[rbase * 64], 16, 0, 0);
    }
#pragma unroll
    for (int i = 0; i < BN / 32; ++i) {
      int rbase = i * 32 + w * 8;
      __builtin_amdgcn_global_load_lds((AS1 u32*)(gB + (size_t)(rbase + lrw) * K + lcl),
                                       (AS3 u32*)&lB[rbase * 64], 16, 0, 0);
    }
    __syncthreads();
#pragma unroll
    for (int kk = 0; kk < 64; kk += 32) {
      bfx8 a[IM], b[4];
#pragma unroll
      for (int i = 0; i < IM; ++i)
        a[i] = *(const bfx8*)&lA[(wr * RPW + i * 16 + r15) * 64 + kk + kg * 8];
#pragma unroll
      for (int j = 0; j < 4; ++j)
        b[j] = *(const bfx8*)&lB[(wc * 64 + j * 16 + r15) * 64 + kk + kg * 8];
#pragma unroll
      for (int i = 0; i < IM; ++i)
#pragma unroll
        for (int j = 0; j < 4; ++j)
          acc[i][j] = __builtin_amdgcn_mfma_f32_16x16x32_bf16(a[i], b[j], acc[i][j], 0, 0, 0);
    }
    __syncthreads();
  }

#pragma unroll
  for (int i = 0; i < IM; ++i) {
#pragma unroll
    for (int j = 0; j < 4; ++j) {
      int col = bm + wc * 64 + j * 16 + r15;
      float bv = bias[col];
#pragma unroll
      for (int r = 0; r < 4; ++r) {
        int row = bn + wr * RPW + i * 16 + kg * 4 + r;
        float v = acc[i][j][r] + bv;
        if (EPI == 1) v = fmaxf(v, 0.f);
        if (EPI == 2) {
          ((float*)Cout)[(size_t)row * M + col] = res[(size_t)row * M + col] + v;
        } else {
          ((u16*)Cout)[(size_t)row * M + col] = f2bf(v);
        }
      }
    }
  }
}

// ---------------- flash attention, head dim 64, swizzled LDS, dbuf staging ----------------
__global__ __launch_bounds__(256, 4) void attn_kernel(const u16* __restrict__ qB,
                                                      const u16* __restrict__ kB,
                                                      const u16* __restrict__ vtB,
                                                      u16* __restrict__ oB,
                                                      int qStride, int kvStride, int Sk) {
  __shared__ __align__(16) u16 lK[2][64 * 64];
  __shared__ __align__(16) u16 lVt[2][64 * 64];
  __shared__ __align__(16) u16 lP[4][16 * 64];
  const int tid = threadIdx.x, lane = tid & 63, w = tid >> 6;
  const int b = blockIdx.y, h = blockIdx.z, qt = blockIdx.x;
  const int r15 = lane & 15, kg = lane >> 4;
  const int srow = lane >> 3;                // row within 8-row stripe
  const int sxcol = ((lane & 7) * 8) ^ (srow * 8);  // swizzled source col (u16)

  const int qs = qt * 64 + w * 16 + r15;
  const u16* qrow = qB + (size_t)(qs * 8 + b) * qStride + h * 64;
  bfx8 qf0 = *(const bfx8*)(qrow + kg * 8);
  bfx8 qf1 = *(const bfx8*)(qrow + 32 + kg * 8);

  const u16* vbase = vtB + ((size_t)(b * 8 + h) * 64) * Sk;

#define STAGE(buf, kt) do {                                                          \
    _Pragma("unroll")                                                                \
    for (int i_ = 0; i_ < 2; ++i_) {                                                 \
      int rb_ = i_ * 32 + w * 8;                                                     \
      int rl_ = rb_ + srow;                                                          \
      const u16* gk_ = kB + (size_t)(((kt) + rl_) * 8 + b) * kvStride + h * 64 + sxcol; \
      __builtin_amdgcn_global_load_lds((AS1 u32*)gk_, (AS3 u32*)&lK[buf][rb_ * 64], 16, 0, 0); \
      const u16* gv_ = vbase + (size_t)rl_ * Sk + (kt) + sxcol;                      \
      __builtin_amdgcn_global_load_lds((AS1 u32*)gv_, (AS3 u32*)&lVt[buf][rb_ * 64], 16, 0, 0); \
    }                                                                                \
  } while (0)

  STAGE(0, 0);
  __syncthreads();

  f32x4 oacc[4] = {};
  float mrow[4], lsum[4];
#pragma unroll
  for (int r = 0; r < 4; ++r) { mrow[r] = -1e30f; lsum[r] = 0.f; }
  const float SC = 0.125f;
  const int nt = Sk / 64;
  const int xr = (r15 & 7) << 4;

  for (int t = 0; t < nt; ++t) {
    int cur = t & 1;
    if (t + 1 < nt) STAGE(cur ^ 1, (t + 1) * 64);

    // S = Q K^T (16 rows x 64 cols per wave), swizzled lK reads
    const char* Kc = (const char*)lK[cur];
    f32x4 sacc[4] = {};
#pragma unroll
    for (int j = 0; j < 4; ++j) {
      const char* kp = Kc + (j * 16 + r15) * 128;
      bfx8 kf0 = *(const bfx8*)(kp + ((kg * 16) ^ xr));
      bfx8 kf1 = *(const bfx8*)(kp + ((64 + kg * 16) ^ xr));
      sacc[j] = __builtin_amdgcn_mfma_f32_16x16x32_bf16(qf0, kf0, sacc[j], 0, 0, 0);
      sacc[j] = __builtin_amdgcn_mfma_f32_16x16x32_bf16(qf1, kf1, sacc[j], 0, 0, 0);
    }

    // online softmax (scale folded into exp)
    float pmax[4];
#pragma unroll
    for (int r = 0; r < 4; ++r)
      pmax[r] = fmaxf(fmaxf(sacc[0][r], sacc[1][r]), fmaxf(sacc[2][r], sacc[3][r]));
#pragma unroll
    for (int m = 1; m < 16; m <<= 1)
#pragma unroll
      for (int r = 0; r < 4; ++r) pmax[r] = fmaxf(pmax[r], __shfl_xor(pmax[r], m));

    float corr[4];
#pragma unroll
    for (int r = 0; r < 4; ++r) {
      float mn = fmaxf(mrow[r], pmax[r]);
      corr[r] = __expf((mrow[r] - mn) * SC);
      mrow[r] = mn;
    }
    float p[4][4];
    float psum[4] = {0.f, 0.f, 0.f, 0.f};
#pragma unroll
    for (int j = 0; j < 4; ++j)
#pragma unroll
      for (int r = 0; r < 4; ++r) {
        float e = __expf((sacc[j][r] - mrow[r]) * SC);
        p[j][r] = e;
        psum[r] += e;
      }
#pragma unroll
    for (int m = 1; m < 16; m <<= 1)
#pragma unroll
      for (int r = 0; r < 4; ++r) psum[r] += __shfl_xor(psum[r], m);
#pragma unroll
    for (int r = 0; r < 4; ++r) lsum[r] = lsum[r] * corr[r] + psum[r];
#pragma unroll
    for (int j = 0; j < 4; ++j)
#pragma unroll
      for (int r = 0; r < 4; ++r) oacc[j][r] *= corr[r];

    // P -> bf16 -> per-wave swizzled LDS (wave-private, no barrier needed)
    char* myP = (char*)lP[w];
#pragma unroll
    for (int j = 0; j < 4; ++j)
#pragma unroll
      for (int r = 0; r < 4; ++r) {
        int row = kg * 4 + r;
        int colB = (j * 32 + r15 * 2) ^ ((row & 7) << 4);
        *(u16*)(myP + row * 128 + colB) = f2bf(p[j][r]);
      }

    // O += P @ V  (swizzled lVt reads)
    const char* Vc = (const char*)lVt[cur];
#pragma unroll
    for (int s2 = 0; s2 < 2; ++s2) {
      bfx8 pf = *(const bfx8*)(myP + r15 * 128 + ((s2 * 64 + kg * 16) ^ xr));
#pragma unroll
      for (int j = 0; j < 4; ++j) {
        const char* vp = Vc + (j * 16 + r15) * 128;
        bfx8 vf = *(const bfx8*)(vp + ((s2 * 64 + kg * 16) ^ xr));
        oacc[j] = __builtin_amdgcn_mfma_f32_16x16x32_bf16(pf, vf, oacc[j], 0, 0, 0);
      }
    }
    __syncthreads();
  }
#undef STAGE

  float inv[4];
#pragma unroll
  for (int r = 0; r < 4; ++r) inv[r] = 1.f / lsum[r];
#pragma unroll
  for (int j = 0; j < 4; ++j)
#pragma unroll
    for (int r = 0; r < 4; ++r) {
      int s = qt * 64 + w * 16 + kg * 4 + r;
      oB[(size_t)(s * 8 + b) * 512 + h * 64 + j * 16 + r15] = f2bf(oacc[j][r] * inv[r]);
    }
}

extern "C" void kernel_launch(void* const* d_in, const int* in_sizes, int n_in,
                              void* d_out, int out_size, void* d_ws, size_t ws_size,
                              hipStream_t stream) {
  const float* rna    = (const float*)d_in[0];
  const float* prot   = (const float*)d_in[1];
  const float* Wqkv_s = (const float*)d_in[2];
  const float* bqkv_s = (const float*)d_in[3];
  const float* Wo_s   = (const float*)d_in[4];
  const float* bo_s   = (const float*)d_in[5];
  const float* Wqkv_c = (const float*)d_in[6];
  const float* bqkv_c = (const float*)d_in[7];
  const float* Wo_c   = (const float*)d_in[8];
  const float* bo_c   = (const float*)d_in[9];
  const float* W1     = (const float*)d_in[10];
  const float* b1     = (const float*)d_in[11];
  const float* W2     = (const float*)d_in[12];
  const float* b2     = (const float*)d_in[13];
  const float* g0  = (const float*)d_in[14];
  const float* be0 = (const float*)d_in[15];
  const float* g11 = (const float*)d_in[16];
  const float* be11= (const float*)d_in[17];
  const float* g12 = (const float*)d_in[18];
  const float* be12= (const float*)d_in[19];
  const float* g2  = (const float*)d_in[20];
  const float* be2 = (const float*)d_in[21];
  float* out = (float*)d_out;

  u16* wbf      = (u16*)d_ws;
  u16* w_qkv_s  = wbf;
  u16* w_o_s    = wbf + 786432;
  u16* w_qkv_c  = wbf + 1048576;
  u16* w_o_c    = wbf + 1835008;
  u16* w_1      = wbf + 2097152;
  u16* w_2      = wbf + 3145728;
  u16* hbuf     = wbf + 4194304;            // 8192x512 bf16 (also Vt_self after qkv gemm)
  u16* qkv      = hbuf + 4194304;           // up to 8192x1536 bf16
  u16* kvc      = qkv + 4194304;            // cross K|V 4096x1024 (reuses self K/V space)
  u16* attnO    = qkv + 12582912;           // 8192x512 bf16
  u16* hp       = attnO + 4194304;          // 4096x512 bf16 (also Vt_cross after kv gemm)
  u16* ffnmid   = qkv;                      // 8192x2048 bf16 (reuses qkv+attnO)

  cvt6_kernel<<<4096, 256, 0, stream>>>(Wqkv_s, Wo_s, Wqkv_c, Wo_c, W1, W2,
                                        w_qkv_s, w_o_s, w_qkv_c, w_o_c, w_1, w_2);

  // self-attention block
  ln_kernel<<<2048, 256, 0, stream>>>(rna, g0, be0, hbuf, 8192);
  gemm_bt<0, 128><<<dim3(12, 64), 256, 0, stream>>>(hbuf, w_qkv_s, bqkv_s, nullptr, qkv, 8192, 1536, 512);
  vt_kernel<<<dim3(16, 8, 8), 256, 0, stream>>>(qkv + 1024, hbuf, 1536, 1024);
  attn_kernel<<<dim3(16, 8, 8), 256, 0, stream>>>(qkv, qkv + 512, hbuf, attnO, 1536, 1536, 1024);
  gemm_bt<2, 64><<<dim3(8, 64), 256, 0, stream>>>(attnO, w_o_s, bo_s, rna, out, 8192, 512, 512);

  // cross-attention block
  ln_kernel<<<2048, 256, 0, stream>>>(out, g11, be11, hbuf, 8192);
  ln_kernel<<<1024, 256, 0, stream>>>(prot, g12, be12, hp, 4096);
  gemm_bt<0, 64><<<dim3(8, 64), 256, 0, stream>>>(hbuf, w_qkv_c, bqkv_c, nullptr, qkv, 8192, 512, 512);
  gemm_bt<0, 64><<<dim3(16, 32), 256, 0, stream>>>(hp, w_qkv_c + 512 * 512, bqkv_c + 512, nullptr, kvc, 4096, 1024, 512);
  vt_kernel<<<dim3(8, 8, 8), 256, 0, stream>>>(kvc + 512, hp, 1024, 512);
  attn_kernel<<<dim3(16, 8, 8), 256, 0, stream>>>(qkv, kvc, hp, attnO, 512, 1024, 512);
  gemm_bt<2, 64><<<dim3(8, 64), 256, 0, stream>>>(attnO, w_o_c, bo_c, out, out, 8192, 512, 512);

  // FFN block
  ln_kernel<<<2048, 256, 0, stream>>>(out, g2, be2, hbuf, 8192);
  gemm_bt<1, 128><<<dim3(16, 64), 256, 0, stream>>>(hbuf, w_1, b1, nullptr, ffnmid, 8192, 2048, 512);
  gemm_bt<2, 64><<<dim3(8, 64), 256, 0, stream>>>(ffnmid, w_2, b2, out, out, 8192, 512, 2048);
}

// Round 3
// 257.923 us; speedup vs baseline: 1.3204x; 1.1140x over previous
//
#include <hip/hip_runtime.h>

typedef unsigned short u16;
typedef unsigned int u32;
typedef u16 u16x8 __attribute__((ext_vector_type(8)));
typedef u16 u16x4 __attribute__((ext_vector_type(4)));
typedef short bfx8 __attribute__((ext_vector_type(8)));
typedef float f32x4 __attribute__((ext_vector_type(4)));

#define AS1 __attribute__((address_space(1)))
#define AS3 __attribute__((address_space(3)))

__device__ __forceinline__ u16 f2bf(float f) {
  union { float f; u32 u; } c; c.f = f;
  u32 u = c.u;
  u += 0x7fffu + ((u >> 16) & 1u);
  return (u16)(u >> 16);
}

__device__ __forceinline__ u32 cvt_pk_bf16(float lo, float hi) {
  u32 r;
  asm("v_cvt_pk_bf16_f32 %0, %1, %2" : "=v"(r) : "v"(lo), "v"(hi));
  return r;
}

__device__ __forceinline__ float fexp2(float x) {
  float r;
  asm("v_exp_f32 %0, %1" : "=v"(r) : "v"(x));
  return r;
}

// ---------------- all-weights fp32 -> bf16 (merged) ----------------
__global__ __launch_bounds__(256) void cvt6_kernel(const float* __restrict__ a0, const float* __restrict__ a1,
                                                   const float* __restrict__ a2, const float* __restrict__ a3,
                                                   const float* __restrict__ a4, const float* __restrict__ a5,
                                                   u16* __restrict__ b0, u16* __restrict__ b1,
                                                   u16* __restrict__ b2, u16* __restrict__ b3,
                                                   u16* __restrict__ b4, u16* __restrict__ b5) {
  int i = blockIdx.x * 256 + threadIdx.x;
  const float* s; u16* d; int off;
  if      (i < 196608) { s = a0; d = b0; off = i; }
  else if (i < 262144) { s = a1; d = b1; off = i - 196608; }
  else if (i < 458752) { s = a2; d = b2; off = i - 262144; }
  else if (i < 524288) { s = a3; d = b3; off = i - 458752; }
  else if (i < 786432) { s = a4; d = b4; off = i - 524288; }
  else                 { s = a5; d = b5; off = i - 786432; }
  float4 v = ((const float4*)s)[off];
  u16x4 o;
  o[0] = f2bf(v.x); o[1] = f2bf(v.y); o[2] = f2bf(v.z); o[3] = f2bf(v.w);
  ((u16x4*)d)[off] = o;
}

// ---------------- LayerNorm (D=512), fp32 in -> bf16 out ----------------
__global__ __launch_bounds__(256) void ln_kernel(const float* __restrict__ x,
                                                 const float* __restrict__ g,
                                                 const float* __restrict__ be,
                                                 u16* __restrict__ out, int ntok) {
  int gw = (blockIdx.x * 256 + threadIdx.x) >> 6;
  int lane = threadIdx.x & 63;
  if (gw >= ntok) return;
  const float4* row = (const float4*)(x + (size_t)gw * 512);
  float4 a = row[2 * lane], b = row[2 * lane + 1];
  float s = a.x + a.y + a.z + a.w + b.x + b.y + b.z + b.w;
  float q = a.x*a.x + a.y*a.y + a.z*a.z + a.w*a.w + b.x*b.x + b.y*b.y + b.z*b.z + b.w*b.w;
#pragma unroll
  for (int m = 1; m < 64; m <<= 1) { s += __shfl_xor(s, m); q += __shfl_xor(q, m); }
  float mean = s * (1.f / 512.f);
  float var = q * (1.f / 512.f) - mean * mean;
  float rs = rsqrtf(var + 1e-5f);
  const float4* g4 = (const float4*)g;
  const float4* b4 = (const float4*)be;
  float4 ga = g4[2 * lane], gb = g4[2 * lane + 1];
  float4 ba = b4[2 * lane], bb = b4[2 * lane + 1];
  u16x8 o;
  o[0] = f2bf((a.x - mean) * rs * ga.x + ba.x);
  o[1] = f2bf((a.y - mean) * rs * ga.y + ba.y);
  o[2] = f2bf((a.z - mean) * rs * ga.z + ba.z);
  o[3] = f2bf((a.w - mean) * rs * ga.w + ba.w);
  o[4] = f2bf((b.x - mean) * rs * gb.x + bb.x);
  o[5] = f2bf((b.y - mean) * rs * gb.y + bb.y);
  o[6] = f2bf((b.z - mean) * rs * gb.z + bb.z);
  o[7] = f2bf((b.w - mean) * rs * gb.w + bb.w);
  ((u16x8*)(out + (size_t)gw * 512))[lane] = o;
}

// ---------------- V transpose: V(s,b,h,d) -> Vt[(b*8+h)*64+d][s] ----------------
__global__ __launch_bounds__(256) void vt_kernel(const u16* __restrict__ vB, u16* __restrict__ vt,
                                                 int stride, int S) {
  __shared__ u16 lt[64 * 68];
  const int t = threadIdx.x;
  const int b = blockIdx.y, h = blockIdx.z;
  const int sr = t >> 3, dc = (t & 7) * 8;
#pragma unroll
  for (int p = 0; p < 2; ++p) {
    int s = blockIdx.x * 64 + sr + p * 32;
    u16x8 v = *(const u16x8*)(vB + (size_t)(s * 8 + b) * stride + h * 64 + dc);
    u16x4 lo, hi;
    lo[0]=v[0]; lo[1]=v[1]; lo[2]=v[2]; lo[3]=v[3];
    hi[0]=v[4]; hi[1]=v[5]; hi[2]=v[6]; hi[3]=v[7];
    *(u16x4*)&lt[(sr + p * 32) * 68 + dc] = lo;
    *(u16x4*)&lt[(sr + p * 32) * 68 + dc + 4] = hi;
  }
  __syncthreads();
#pragma unroll
  for (int p = 0; p < 2; ++p) {
    int d = sr + p * 32;
    u16x8 o;
#pragma unroll
    for (int e = 0; e < 8; ++e) o[e] = lt[(dc + e) * 68 + d];
    *(u16x8*)(vt + ((size_t)(b * 8 + h) * 64 + d) * S + blockIdx.x * 64 + dc) = o;
  }
}

// ---------------- GEMM: C(N,M) = A(N,K)bf16 @ W(M,K)bf16^T + bias ----------------
// EPI: 0 = bf16 out, 1 = bf16 out + relu, 2 = fp32 out + residual add
template <int EPI, int BN>
__global__ __launch_bounds__(256) void gemm_bt(const u16* __restrict__ A,
                                               const u16* __restrict__ Bw,
                                               const float* __restrict__ bias,
                                               const float* __restrict__ res,
                                               void* __restrict__ Cout,
                                               int N, int M, int K) {
  constexpr int WC = BN / 64;
  constexpr int WR = 4 / WC;
  constexpr int RPW = 128 / WR;
  constexpr int IM = RPW / 16;
  __shared__ __align__(16) u16 lA[128 * 64];
  __shared__ __align__(16) u16 lB[BN * 64];
  const int tid = threadIdx.x;
  const int lane = tid & 63, w = tid >> 6;
  const int wr = w / WC, wc = w % WC;
  const int bn = blockIdx.y * 128;
  const int bm = blockIdx.x * BN;
  const int r15 = lane & 15, kg = lane >> 4;

  f32x4 acc[IM][4] = {};

  const int lrw = lane >> 3, lcl = (lane & 7) * 8;

  for (int k0 = 0; k0 < K; k0 += 64) {
    const u16* gA = A + (size_t)bn * K + k0;
    const u16* gB = Bw + (size_t)bm * K + k0;
#pragma unroll
    for (int i = 0; i < 4; ++i) {
      int rbase = i * 32 + w * 8;
      __builtin_amdgcn_global_load_lds((AS1 u32*)(gA + (size_t)(rbase + lrw) * K + lcl),
                                       (AS3 u32*)&lA[rbase * 64], 16, 0, 0);
    }
#pragma unroll
    for (int i = 0; i < BN / 32; ++i) {
      int rbase = i * 32 + w * 8;
      __builtin_amdgcn_global_load_lds((AS1 u32*)(gB + (size_t)(rbase + lrw) * K + lcl),
                                       (AS3 u32*)&lB[rbase * 64], 16, 0, 0);
    }
    __syncthreads();
#pragma unroll
    for (int kk = 0; kk < 64; kk += 32) {
      bfx8 a[IM], b[4];
#pragma unroll
      for (int i = 0; i < IM; ++i)
        a[i] = *(const bfx8*)&lA[(wr * RPW + i * 16 + r15) * 64 + kk + kg * 8];
#pragma unroll
      for (int j = 0; j < 4; ++j)
        b[j] = *(const bfx8*)&lB[(wc * 64 + j * 16 + r15) * 64 + kk + kg * 8];
#pragma unroll
      for (int i = 0; i < IM; ++i)
#pragma unroll
        for (int j = 0; j < 4; ++j)
          acc[i][j] = __builtin_amdgcn_mfma_f32_16x16x32_bf16(a[i], b[j], acc[i][j], 0, 0, 0);
    }
    __syncthreads();
  }

#pragma unroll
  for (int i = 0; i < IM; ++i) {
#pragma unroll
    for (int j = 0; j < 4; ++j) {
      int col = bm + wc * 64 + j * 16 + r15;
      float bv = bias[col];
#pragma unroll
      for (int r = 0; r < 4; ++r) {
        int row = bn + wr * RPW + i * 16 + kg * 4 + r;
        float v = acc[i][j][r] + bv;
        if (EPI == 1) v = fmaxf(v, 0.f);
        if (EPI == 2) {
          ((float*)Cout)[(size_t)row * M + col] = res[(size_t)row * M + col] + v;
        } else {
          ((u16*)Cout)[(size_t)row * M + col] = f2bf(v);
        }
      }
    }
  }
}

// ---------------- flash attention, swapped-QK^T lane-local softmax ----------------
// Per wave: 16 q-rows (q = lane&15), K-tile 64. S^T = mfma(K,Q) -> lane holds
// S[k = j*16 + kg*4 + r][q = r15]. Softmax: in-lane 16-reduce + 2 shuffles.
// PV: O^T = mfma(Vt, P^T) with P^T routed via per-wave swizzled LDS (packed b32).
__global__ __launch_bounds__(256, 4) void attn_kernel(const u16* __restrict__ qB,
                                                      const u16* __restrict__ kB,
                                                      const u16* __restrict__ vtB,
                                                      u16* __restrict__ oB,
                                                      int qStride, int kvStride, int Sk) {
  __shared__ __align__(16) u16 lK[2][64 * 64];
  __shared__ __align__(16) u16 lVt[2][64 * 64];
  __shared__ __align__(16) u16 lP[4][16 * 64];
  const int tid = threadIdx.x, lane = tid & 63, w = tid >> 6;
  const int b = blockIdx.y, h = blockIdx.z, qt = blockIdx.x;
  const int r15 = lane & 15, kg = lane >> 4;
  const int srow = lane >> 3;
  const int sxcol = ((lane & 7) * 8) ^ (srow * 8);

  const int qs = qt * 64 + w * 16 + r15;
  const u16* qrow = qB + (size_t)(qs * 8 + b) * qStride + h * 64;
  bfx8 qf0 = *(const bfx8*)(qrow + kg * 8);
  bfx8 qf1 = *(const bfx8*)(qrow + 32 + kg * 8);

  const u16* vbase = vtB + ((size_t)(b * 8 + h) * 64) * Sk;
  // staging pointers (advance per tile)
  const u16* kpA = kB + ((size_t)(w * 8 + srow) * 8 + b) * kvStride + h * 64 + sxcol;
  const u16* kpB = kpA + (size_t)32 * 8 * kvStride;
  const size_t kAdv = (size_t)64 * 8 * kvStride;
  const u16* vpA = vbase + (size_t)(w * 8 + srow) * Sk + sxcol;
  const u16* vpB = vpA + (size_t)32 * Sk;

#define STAGE(buf, t) do {                                                            \
    __builtin_amdgcn_global_load_lds((AS1 u32*)(kpA + (size_t)(t) * kAdv),            \
                                     (AS3 u32*)&lK[buf][(w * 8) * 64], 16, 0, 0);     \
    __builtin_amdgcn_global_load_lds((AS1 u32*)(kpB + (size_t)(t) * kAdv),            \
                                     (AS3 u32*)&lK[buf][(32 + w * 8) * 64], 16, 0, 0);\
    __builtin_amdgcn_global_load_lds((AS1 u32*)(vpA + (size_t)(t) * 64),              \
                                     (AS3 u32*)&lVt[buf][(w * 8) * 64], 16, 0, 0);    \
    __builtin_amdgcn_global_load_lds((AS1 u32*)(vpB + (size_t)(t) * 64),              \
                                     (AS3 u32*)&lVt[buf][(32 + w * 8) * 64], 16, 0, 0);\
  } while (0)

  STAGE(0, 0);
  __syncthreads();

  f32x4 oacc[4] = {};
  float mrow = -1e30f, lsum = 0.f;
  const float C2 = 0.125f * 1.44269504088896340736f;  // scale * log2(e)
  const int nt = Sk / 64;
  const int xr = (r15 & 7) << 4;
  char* myP = (char*)lP[w];

  for (int t = 0; t < nt; ++t) {
    int cur = t & 1;
    if (t + 1 < nt) STAGE(cur ^ 1, t + 1);

    // S^T = mfma(K, Q): st[j][r] = S[k = j*16+kg*4+r][q = r15]
    const char* Kc = (const char*)lK[cur];
    f32x4 st[4] = {};
#pragma unroll
    for (int j = 0; j < 4; ++j) {
      const char* kp = Kc + (j * 16 + r15) * 128;
      bfx8 kf0 = *(const bfx8*)(kp + ((kg * 16) ^ xr));
      bfx8 kf1 = *(const bfx8*)(kp + ((64 + kg * 16) ^ xr));
      st[j] = __builtin_amdgcn_mfma_f32_16x16x32_bf16(kf0, qf0, st[j], 0, 0, 0);
      st[j] = __builtin_amdgcn_mfma_f32_16x16x32_bf16(kf1, qf1, st[j], 0, 0, 0);
    }

    // lane-local max over 16 values + 2 cross-group shuffles
    float m0 = fmaxf(fmaxf(fmaxf(st[0][0], st[0][1]), fmaxf(st[0][2], st[0][3])),
                     fmaxf(fmaxf(st[1][0], st[1][1]), fmaxf(st[1][2], st[1][3])));
    float m1 = fmaxf(fmaxf(fmaxf(st[2][0], st[2][1]), fmaxf(st[2][2], st[2][3])),
                     fmaxf(fmaxf(st[3][0], st[3][1]), fmaxf(st[3][2], st[3][3])));
    m0 = fmaxf(m0, m1);
    m0 = fmaxf(m0, __shfl_xor(m0, 16));
    m0 = fmaxf(m0, __shfl_xor(m0, 32));

    float mn = fmaxf(mrow, m0);
    float corr = fexp2((mrow - mn) * C2);
    mrow = mn;
    float bc = -mn * C2;

    float p[4][4];
#pragma unroll
    for (int j = 0; j < 4; ++j)
#pragma unroll
      for (int r = 0; r < 4; ++r)
        p[j][r] = fexp2(fmaf(st[j][r], C2, bc));

    float ps = ((p[0][0] + p[0][1]) + (p[0][2] + p[0][3]))
             + ((p[1][0] + p[1][1]) + (p[1][2] + p[1][3]))
             + ((p[2][0] + p[2][1]) + (p[2][2] + p[2][3]))
             + ((p[3][0] + p[3][1]) + (p[3][2] + p[3][3]));
    ps += __shfl_xor(ps, 16);
    ps += __shfl_xor(ps, 32);
    lsum = lsum * corr + ps;
#pragma unroll
    for (int jd = 0; jd < 4; ++jd)
#pragma unroll
      for (int r = 0; r < 4; ++r) oacc[jd][r] *= corr;

    // P^T -> bf16 pairs -> per-wave swizzled LDS (8 packed b32 writes)
#pragma unroll
    for (int j = 0; j < 4; ++j)
#pragma unroll
      for (int h2 = 0; h2 < 2; ++h2) {
        u32 pk = cvt_pk_bf16(p[j][2 * h2], p[j][2 * h2 + 1]);
        int k0b = (j * 16 + kg * 4 + 2 * h2) * 2;
        *(u32*)(myP + r15 * 128 + (k0b ^ xr)) = pk;
      }

    // O^T += Vt @ P^T  (A = Vt rows=d, B = P^T cols=q)
    const char* Vc = (const char*)lVt[cur];
#pragma unroll
    for (int s2 = 0; s2 < 2; ++s2) {
      bfx8 ptf = *(const bfx8*)(myP + r15 * 128 + ((s2 * 64 + kg * 16) ^ xr));
#pragma unroll
      for (int jd = 0; jd < 4; ++jd) {
        const char* vp = Vc + (jd * 16 + r15) * 128;
        bfx8 vf = *(const bfx8*)(vp + ((s2 * 64 + kg * 16) ^ xr));
        oacc[jd] = __builtin_amdgcn_mfma_f32_16x16x32_bf16(vf, ptf, oacc[jd], 0, 0, 0);
      }
    }
    __syncthreads();
  }
#undef STAGE

  // lane holds O[q = r15][d = jd*16 + kg*4 + r]
  float inv = 1.f / lsum;
  const int s = qt * 64 + w * 16 + r15;
  u16* orow = oB + (size_t)(s * 8 + b) * 512 + h * 64;
#pragma unroll
  for (int jd = 0; jd < 4; ++jd) {
    u32 p0 = cvt_pk_bf16(oacc[jd][0] * inv, oacc[jd][1] * inv);
    u32 p1 = cvt_pk_bf16(oacc[jd][2] * inv, oacc[jd][3] * inv);
    *(u32*)(orow + jd * 16 + kg * 4) = p0;
    *(u32*)(orow + jd * 16 + kg * 4 + 2) = p1;
  }
}

extern "C" void kernel_launch(void* const* d_in, const int* in_sizes, int n_in,
                              void* d_out, int out_size, void* d_ws, size_t ws_size,
                              hipStream_t stream) {
  const float* rna    = (const float*)d_in[0];
  const float* prot   = (const float*)d_in[1];
  const float* Wqkv_s = (const float*)d_in[2];
  const float* bqkv_s = (const float*)d_in[3];
  const float* Wo_s   = (const float*)d_in[4];
  const float* bo_s   = (const float*)d_in[5];
  const float* Wqkv_c = (const float*)d_in[6];
  const float* bqkv_c = (const float*)d_in[7];
  const float* Wo_c   = (const float*)d_in[8];
  const float* bo_c   = (const float*)d_in[9];
  const float* W1     = (const float*)d_in[10];
  const float* b1     = (const float*)d_in[11];
  const float* W2     = (const float*)d_in[12];
  const float* b2     = (const float*)d_in[13];
  const float* g0  = (const float*)d_in[14];
  const float* be0 = (const float*)d_in[15];
  const float* g11 = (const float*)d_in[16];
  const float* be11= (const float*)d_in[17];
  const float* g12 = (const float*)d_in[18];
  const float* be12= (const float*)d_in[19];
  const float* g2  = (const float*)d_in[20];
  const float* be2 = (const float*)d_in[21];
  float* out = (float*)d_out;

  u16* wbf      = (u16*)d_ws;
  u16* w_qkv_s  = wbf;
  u16* w_o_s    = wbf + 786432;
  u16* w_qkv_c  = wbf + 1048576;
  u16* w_o_c    = wbf + 1835008;
  u16* w_1      = wbf + 2097152;
  u16* w_2      = wbf + 3145728;
  u16* hbuf     = wbf + 4194304;            // 8192x512 bf16 (also Vt_self)
  u16* qkv      = hbuf + 4194304;           // up to 8192x1536 bf16
  u16* kvc      = qkv + 4194304;            // cross K|V 4096x1024
  u16* attnO    = qkv + 12582912;           // 8192x512 bf16
  u16* hp       = attnO + 4194304;          // 4096x512 bf16 (also Vt_cross)
  u16* ffnmid   = qkv;                      // 8192x2048 bf16

  cvt6_kernel<<<4096, 256, 0, stream>>>(Wqkv_s, Wo_s, Wqkv_c, Wo_c, W1, W2,
                                        w_qkv_s, w_o_s, w_qkv_c, w_o_c, w_1, w_2);

  // self-attention block
  ln_kernel<<<2048, 256, 0, stream>>>(rna, g0, be0, hbuf, 8192);
  gemm_bt<0, 128><<<dim3(12, 64), 256, 0, stream>>>(hbuf, w_qkv_s, bqkv_s, nullptr, qkv, 8192, 1536, 512);
  vt_kernel<<<dim3(16, 8, 8), 256, 0, stream>>>(qkv + 1024, hbuf, 1536, 1024);
  attn_kernel<<<dim3(16, 8, 8), 256, 0, stream>>>(qkv, qkv + 512, hbuf, attnO, 1536, 1536, 1024);
  gemm_bt<2, 64><<<dim3(8, 64), 256, 0, stream>>>(attnO, w_o_s, bo_s, rna, out, 8192, 512, 512);

  // cross-attention block
  ln_kernel<<<2048, 256, 0, stream>>>(out, g11, be11, hbuf, 8192);
  ln_kernel<<<1024, 256, 0, stream>>>(prot, g12, be12, hp, 4096);
  gemm_bt<0, 64><<<dim3(8, 64), 256, 0, stream>>>(hbuf, w_qkv_c, bqkv_c, nullptr, qkv, 8192, 512, 512);
  gemm_bt<0, 64><<<dim3(16, 32), 256, 0, stream>>>(hp, w_qkv_c + 512 * 512, bqkv_c + 512, nullptr, kvc, 4096, 1024, 512);
  vt_kernel<<<dim3(8, 8, 8), 256, 0, stream>>>(kvc + 512, hp, 1024, 512);
  attn_kernel<<<dim3(16, 8, 8), 256, 0, stream>>>(qkv, kvc, hp, attnO, 512, 1024, 512);
  gemm_bt<2, 64><<<dim3(8, 64), 256, 0, stream>>>(attnO, w_o_c, bo_c, out, out, 8192, 512, 512);

  // FFN block
  ln_kernel<<<2048, 256, 0, stream>>>(out, g2, be2, hbuf, 8192);
  gemm_bt<1, 128><<<dim3(16, 64), 256, 0, stream>>>(hbuf, w_1, b1, nullptr, ffnmid, 8192, 2048, 512);
  gemm_bt<2, 64><<<dim3(8, 64), 256, 0, stream>>>(ffnmid, w_2, b2, out, out, 8192, 512, 2048);
}

// Round 4
// 222.204 us; speedup vs baseline: 1.5326x; 1.1607x over previous
//
#include <hip/hip_runtime.h>

typedef unsigned short u16;
typedef unsigned int u32;
typedef u16 u16x8 __attribute__((ext_vector_type(8)));
typedef u16 u16x4 __attribute__((ext_vector_type(4)));
typedef short bfx8 __attribute__((ext_vector_type(8)));
typedef float f32x4 __attribute__((ext_vector_type(4)));

#define AS1 __attribute__((address_space(1)))
#define AS3 __attribute__((address_space(3)))

__device__ __forceinline__ u16 f2bf(float f) {
  union { float f; u32 u; } c; c.f = f;
  u32 u = c.u;
  u += 0x7fffu + ((u >> 16) & 1u);
  return (u16)(u >> 16);
}

__device__ __forceinline__ u32 cvt_pk_bf16(float lo, float hi) {
  u32 r;
  asm("v_cvt_pk_bf16_f32 %0, %1, %2" : "=v"(r) : "v"(lo), "v"(hi));
  return r;
}

__device__ __forceinline__ float fexp2(float x) {
  float r;
  asm("v_exp_f32 %0, %1" : "=v"(r) : "v"(x));
  return r;
}

// ---------------- all-weights fp32 -> bf16 (merged) ----------------
__global__ __launch_bounds__(256) void cvt6_kernel(const float* __restrict__ a0, const float* __restrict__ a1,
                                                   const float* __restrict__ a2, const float* __restrict__ a3,
                                                   const float* __restrict__ a4, const float* __restrict__ a5,
                                                   u16* __restrict__ b0, u16* __restrict__ b1,
                                                   u16* __restrict__ b2, u16* __restrict__ b3,
                                                   u16* __restrict__ b4, u16* __restrict__ b5) {
  int i = blockIdx.x * 256 + threadIdx.x;
  const float* s; u16* d; int off;
  if      (i < 196608) { s = a0; d = b0; off = i; }
  else if (i < 262144) { s = a1; d = b1; off = i - 196608; }
  else if (i < 458752) { s = a2; d = b2; off = i - 262144; }
  else if (i < 524288) { s = a3; d = b3; off = i - 458752; }
  else if (i < 786432) { s = a4; d = b4; off = i - 524288; }
  else                 { s = a5; d = b5; off = i - 786432; }
  float4 v = ((const float4*)s)[off];
  u16x4 o;
  o[0] = f2bf(v.x); o[1] = f2bf(v.y); o[2] = f2bf(v.z); o[3] = f2bf(v.w);
  ((u16x4*)d)[off] = o;
}

// ---------------- LayerNorm (D=512), fp32 in -> bf16 out ----------------
__global__ __launch_bounds__(256) void ln_kernel(const float* __restrict__ x,
                                                 const float* __restrict__ g,
                                                 const float* __restrict__ be,
                                                 u16* __restrict__ out, int ntok) {
  int gw = (blockIdx.x * 256 + threadIdx.x) >> 6;
  int lane = threadIdx.x & 63;
  if (gw >= ntok) return;
  const float4* row = (const float4*)(x + (size_t)gw * 512);
  float4 a = row[2 * lane], b = row[2 * lane + 1];
  float s = a.x + a.y + a.z + a.w + b.x + b.y + b.z + b.w;
  float q = a.x*a.x + a.y*a.y + a.z*a.z + a.w*a.w + b.x*b.x + b.y*b.y + b.z*b.z + b.w*b.w;
#pragma unroll
  for (int m = 1; m < 64; m <<= 1) { s += __shfl_xor(s, m); q += __shfl_xor(q, m); }
  float mean = s * (1.f / 512.f);
  float var = q * (1.f / 512.f) - mean * mean;
  float rs = rsqrtf(var + 1e-5f);
  const float4* g4 = (const float4*)g;
  const float4* b4 = (const float4*)be;
  float4 ga = g4[2 * lane], gb = g4[2 * lane + 1];
  float4 ba = b4[2 * lane], bb = b4[2 * lane + 1];
  u16x8 o;
  o[0] = f2bf((a.x - mean) * rs * ga.x + ba.x);
  o[1] = f2bf((a.y - mean) * rs * ga.y + ba.y);
  o[2] = f2bf((a.z - mean) * rs * ga.z + ba.z);
  o[3] = f2bf((a.w - mean) * rs * ga.w + ba.w);
  o[4] = f2bf((b.x - mean) * rs * gb.x + bb.x);
  o[5] = f2bf((b.y - mean) * rs * gb.y + bb.y);
  o[6] = f2bf((b.z - mean) * rs * gb.z + bb.z);
  o[7] = f2bf((b.w - mean) * rs * gb.w + bb.w);
  ((u16x8*)(out + (size_t)gw * 512))[lane] = o;
}

// ---------------- V transpose: V(s,b,h,d) -> Vt[(b*8+h)*64+d][s] ----------------
__global__ __launch_bounds__(256) void vt_kernel(const u16* __restrict__ vB, u16* __restrict__ vt,
                                                 int stride, int S) {
  __shared__ u16 lt[64 * 68];
  const int t = threadIdx.x;
  const int b = blockIdx.y, h = blockIdx.z;
  const int sr = t >> 3, dc = (t & 7) * 8;
#pragma unroll
  for (int p = 0; p < 2; ++p) {
    int s = blockIdx.x * 64 + sr + p * 32;
    u16x8 v = *(const u16x8*)(vB + (size_t)(s * 8 + b) * stride + h * 64 + dc);
    u16x4 lo, hi;
    lo[0]=v[0]; lo[1]=v[1]; lo[2]=v[2]; lo[3]=v[3];
    hi[0]=v[4]; hi[1]=v[5]; hi[2]=v[6]; hi[3]=v[7];
    *(u16x4*)&lt[(sr + p * 32) * 68 + dc] = lo;
    *(u16x4*)&lt[(sr + p * 32) * 68 + dc + 4] = hi;
  }
  __syncthreads();
#pragma unroll
  for (int p = 0; p < 2; ++p) {
    int d = sr + p * 32;
    u16x8 o;
#pragma unroll
    for (int e = 0; e < 8; ++e) o[e] = lt[(dc + e) * 68 + d];
    *(u16x8*)(vt + ((size_t)(b * 8 + h) * 64 + d) * S + blockIdx.x * 64 + dc) = o;
  }
}

// ---------------- GEMM: C(N,M) = A(N,K)bf16 @ W(M,K)bf16^T + bias ----------------
// EPI: 0 = bf16 out, 1 = bf16 out + relu, 2 = fp32 out + residual add
// T1 XCD-swizzled block ids (grid size must be a multiple of 8).
// T2 XOR-swizzled LDS (pre-swizzled global source + swizzled frag reads).
template <int EPI, int BN>
__global__ __launch_bounds__(256) void gemm_bt(const u16* __restrict__ A,
                                               const u16* __restrict__ Bw,
                                               const float* __restrict__ bias,
                                               const float* __restrict__ res,
                                               void* __restrict__ Cout,
                                               int N, int M, int K) {
  constexpr int WC = BN / 64;
  constexpr int WR = 4 / WC;
  constexpr int RPW = 128 / WR;
  constexpr int IM = RPW / 16;
  __shared__ __align__(16) u16 lA[128 * 64];
  __shared__ __align__(16) u16 lB[BN * 64];
  const int tid = threadIdx.x;
  const int lane = tid & 63, w = tid >> 6;
  const int wr = w / WC, wc = w % WC;
  // XCD-aware block swizzle: dispatch id -> (xcd, seq); xcd owns contiguous band
  const int nwg = gridDim.x * gridDim.y;
  const int id = blockIdx.y * gridDim.x + blockIdx.x;
  const int swz = (id & 7) * (nwg >> 3) + (id >> 3);
  const int bn = (swz / gridDim.x) * 128;
  const int bm = (swz % gridDim.x) * BN;
  const int r15 = lane & 15, kg = lane >> 4;
  const int xr = (r15 & 7) << 4;

  f32x4 acc[IM][4] = {};

  const int lrw = lane >> 3;
  const int lcl = (((lane & 7) * 8) ^ (lrw * 8));  // swizzled source col (u16)

  for (int k0 = 0; k0 < K; k0 += 64) {
    const u16* gA = A + (size_t)bn * K + k0;
    const u16* gB = Bw + (size_t)bm * K + k0;
#pragma unroll
    for (int i = 0; i < 4; ++i) {
      int rbase = i * 32 + w * 8;
      __builtin_amdgcn_global_load_lds((AS1 u32*)(gA + (size_t)(rbase + lrw) * K + lcl),
                                       (AS3 u32*)&lA[rbase * 64], 16, 0, 0);
    }
#pragma unroll
    for (int i = 0; i < BN / 32; ++i) {
      int rbase = i * 32 + w * 8;
      __builtin_amdgcn_global_load_lds((AS1 u32*)(gB + (size_t)(rbase + lrw) * K + lcl),
                                       (AS3 u32*)&lB[rbase * 64], 16, 0, 0);
    }
    __syncthreads();
    const char* Ac = (const char*)lA;
    const char* Bc = (const char*)lB;
#pragma unroll
    for (int kk = 0; kk < 64; kk += 32) {
      bfx8 a[IM], b[4];
#pragma unroll
      for (int i = 0; i < IM; ++i)
        a[i] = *(const bfx8*)(Ac + (wr * RPW + i * 16 + r15) * 128 + ((kk * 2 + kg * 16) ^ xr));
#pragma unroll
      for (int j = 0; j < 4; ++j)
        b[j] = *(const bfx8*)(Bc + (wc * 64 + j * 16 + r15) * 128 + ((kk * 2 + kg * 16) ^ xr));
#pragma unroll
      for (int i = 0; i < IM; ++i)
#pragma unroll
        for (int j = 0; j < 4; ++j)
          acc[i][j] = __builtin_amdgcn_mfma_f32_16x16x32_bf16(a[i], b[j], acc[i][j], 0, 0, 0);
    }
    __syncthreads();
  }

#pragma unroll
  for (int i = 0; i < IM; ++i) {
#pragma unroll
    for (int j = 0; j < 4; ++j) {
      int col = bm + wc * 64 + j * 16 + r15;
      float bv = bias[col];
#pragma unroll
      for (int r = 0; r < 4; ++r) {
        int row = bn + wr * RPW + i * 16 + kg * 4 + r;
        float v = acc[i][j][r] + bv;
        if (EPI == 1) v = fmaxf(v, 0.f);
        if (EPI == 2) {
          ((float*)Cout)[(size_t)row * M + col] = res[(size_t)row * M + col] + v;
        } else {
          ((u16*)Cout)[(size_t)row * M + col] = f2bf(v);
        }
      }
    }
  }
}

// ---------------- flash attention, swapped-QK^T lane-local softmax ----------------
__global__ __launch_bounds__(256, 4) void attn_kernel(const u16* __restrict__ qB,
                                                      const u16* __restrict__ kB,
                                                      const u16* __restrict__ vtB,
                                                      u16* __restrict__ oB,
                                                      int qStride, int kvStride, int Sk) {
  __shared__ __align__(16) u16 lK[2][64 * 64];
  __shared__ __align__(16) u16 lVt[2][64 * 64];
  __shared__ __align__(16) u16 lP[4][16 * 64];
  const int tid = threadIdx.x, lane = tid & 63, w = tid >> 6;
  const int b = blockIdx.y, h = blockIdx.z, qt = blockIdx.x;
  const int r15 = lane & 15, kg = lane >> 4;
  const int srow = lane >> 3;
  const int sxcol = ((lane & 7) * 8) ^ (srow * 8);

  const int qs = qt * 64 + w * 16 + r15;
  const u16* qrow = qB + (size_t)(qs * 8 + b) * qStride + h * 64;
  bfx8 qf0 = *(const bfx8*)(qrow + kg * 8);
  bfx8 qf1 = *(const bfx8*)(qrow + 32 + kg * 8);

  const u16* vbase = vtB + ((size_t)(b * 8 + h) * 64) * Sk;
  const u16* kpA = kB + ((size_t)(w * 8 + srow) * 8 + b) * kvStride + h * 64 + sxcol;
  const u16* kpB = kpA + (size_t)32 * 8 * kvStride;
  const size_t kAdv = (size_t)64 * 8 * kvStride;
  const u16* vpA = vbase + (size_t)(w * 8 + srow) * Sk + sxcol;
  const u16* vpB = vpA + (size_t)32 * Sk;

#define STAGE(buf, t) do {                                                            \
    __builtin_amdgcn_global_load_lds((AS1 u32*)(kpA + (size_t)(t) * kAdv),            \
                                     (AS3 u32*)&lK[buf][(w * 8) * 64], 16, 0, 0);     \
    __builtin_amdgcn_global_load_lds((AS1 u32*)(kpB + (size_t)(t) * kAdv),            \
                                     (AS3 u32*)&lK[buf][(32 + w * 8) * 64], 16, 0, 0);\
    __builtin_amdgcn_global_load_lds((AS1 u32*)(vpA + (size_t)(t) * 64),              \
                                     (AS3 u32*)&lVt[buf][(w * 8) * 64], 16, 0, 0);    \
    __builtin_amdgcn_global_load_lds((AS1 u32*)(vpB + (size_t)(t) * 64),              \
                                     (AS3 u32*)&lVt[buf][(32 + w * 8) * 64], 16, 0, 0);\
  } while (0)

  STAGE(0, 0);
  __syncthreads();

  f32x4 oacc[4] = {};
  float mrow = -1e30f, lsum = 0.f;
  const float C2 = 0.125f * 1.44269504088896340736f;
  const int nt = Sk / 64;
  const int xr = (r15 & 7) << 4;
  char* myP = (char*)lP[w];

  for (int t = 0; t < nt; ++t) {
    int cur = t & 1;
    if (t + 1 < nt) STAGE(cur ^ 1, t + 1);

    const char* Kc = (const char*)lK[cur];
    f32x4 st[4] = {};
    __builtin_amdgcn_s_setprio(1);
#pragma unroll
    for (int j = 0; j < 4; ++j) {
      const char* kp = Kc + (j * 16 + r15) * 128;
      bfx8 kf0 = *(const bfx8*)(kp + ((kg * 16) ^ xr));
      bfx8 kf1 = *(const bfx8*)(kp + ((64 + kg * 16) ^ xr));
      st[j] = __builtin_amdgcn_mfma_f32_16x16x32_bf16(kf0, qf0, st[j], 0, 0, 0);
      st[j] = __builtin_amdgcn_mfma_f32_16x16x32_bf16(kf1, qf1, st[j], 0, 0, 0);
    }
    __builtin_amdgcn_s_setprio(0);

    float m0 = fmaxf(fmaxf(fmaxf(st[0][0], st[0][1]), fmaxf(st[0][2], st[0][3])),
                     fmaxf(fmaxf(st[1][0], st[1][1]), fmaxf(st[1][2], st[1][3])));
    float m1 = fmaxf(fmaxf(fmaxf(st[2][0], st[2][1]), fmaxf(st[2][2], st[2][3])),
                     fmaxf(fmaxf(st[3][0], st[3][1]), fmaxf(st[3][2], st[3][3])));
    m0 = fmaxf(m0, m1);
    m0 = fmaxf(m0, __shfl_xor(m0, 16));
    m0 = fmaxf(m0, __shfl_xor(m0, 32));

    float mn = fmaxf(mrow, m0);
    float corr = fexp2((mrow - mn) * C2);
    mrow = mn;
    float bc = -mn * C2;

    float p[4][4];
#pragma unroll
    for (int j = 0; j < 4; ++j)
#pragma unroll
      for (int r = 0; r < 4; ++r)
        p[j][r] = fexp2(fmaf(st[j][r], C2, bc));

    float ps = ((p[0][0] + p[0][1]) + (p[0][2] + p[0][3]))
             + ((p[1][0] + p[1][1]) + (p[1][2] + p[1][3]))
             + ((p[2][0] + p[2][1]) + (p[2][2] + p[2][3]))
             + ((p[3][0] + p[3][1]) + (p[3][2] + p[3][3]));
    ps += __shfl_xor(ps, 16);
    ps += __shfl_xor(ps, 32);
    lsum = lsum * corr + ps;
#pragma unroll
    for (int jd = 0; jd < 4; ++jd)
#pragma unroll
      for (int r = 0; r < 4; ++r) oacc[jd][r] *= corr;

#pragma unroll
    for (int j = 0; j < 4; ++j)
#pragma unroll
      for (int h2 = 0; h2 < 2; ++h2) {
        u32 pk = cvt_pk_bf16(p[j][2 * h2], p[j][2 * h2 + 1]);
        int k0b = (j * 16 + kg * 4 + 2 * h2) * 2;
        *(u32*)(myP + r15 * 128 + (k0b ^ xr)) = pk;
      }

    const char* Vc = (const char*)lVt[cur];
    __builtin_amdgcn_s_setprio(1);
#pragma unroll
    for (int s2 = 0; s2 < 2; ++s2) {
      bfx8 ptf = *(const bfx8*)(myP + r15 * 128 + ((s2 * 64 + kg * 16) ^ xr));
#pragma unroll
      for (int jd = 0; jd < 4; ++jd) {
        const char* vp = Vc + (jd * 16 + r15) * 128;
        bfx8 vf = *(const bfx8*)(vp + ((s2 * 64 + kg * 16) ^ xr));
        oacc[jd] = __builtin_amdgcn_mfma_f32_16x16x32_bf16(vf, ptf, oacc[jd], 0, 0, 0);
      }
    }
    __builtin_amdgcn_s_setprio(0);
    __syncthreads();
  }
#undef STAGE

  float inv = 1.f / lsum;
  const int s = qt * 64 + w * 16 + r15;
  u16* orow = oB + (size_t)(s * 8 + b) * 512 + h * 64;
#pragma unroll
  for (int jd = 0; jd < 4; ++jd) {
    u32 p0 = cvt_pk_bf16(oacc[jd][0] * inv, oacc[jd][1] * inv);
    u32 p1 = cvt_pk_bf16(oacc[jd][2] * inv, oacc[jd][3] * inv);
    *(u32*)(orow + jd * 16 + kg * 4) = p0;
    *(u32*)(orow + jd * 16 + kg * 4 + 2) = p1;
  }
}

extern "C" void kernel_launch(void* const* d_in, const int* in_sizes, int n_in,
                              void* d_out, int out_size, void* d_ws, size_t ws_size,
                              hipStream_t stream) {
  const float* rna    = (const float*)d_in[0];
  const float* prot   = (const float*)d_in[1];
  const float* Wqkv_s = (const float*)d_in[2];
  const float* bqkv_s = (const float*)d_in[3];
  const float* Wo_s   = (const float*)d_in[4];
  const float* bo_s   = (const float*)d_in[5];
  const float* Wqkv_c = (const float*)d_in[6];
  const float* bqkv_c = (const float*)d_in[7];
  const float* Wo_c   = (const float*)d_in[8];
  const float* bo_c   = (const float*)d_in[9];
  const float* W1     = (const float*)d_in[10];
  const float* b1     = (const float*)d_in[11];
  const float* W2     = (const float*)d_in[12];
  const float* b2     = (const float*)d_in[13];
  const float* g0  = (const float*)d_in[14];
  const float* be0 = (const float*)d_in[15];
  const float* g11 = (const float*)d_in[16];
  const float* be11= (const float*)d_in[17];
  const float* g12 = (const float*)d_in[18];
  const float* be12= (const float*)d_in[19];
  const float* g2  = (const float*)d_in[20];
  const float* be2 = (const float*)d_in[21];
  float* out = (float*)d_out;

  u16* wbf      = (u16*)d_ws;
  u16* w_qkv_s  = wbf;
  u16* w_o_s    = wbf + 786432;
  u16* w_qkv_c  = wbf + 1048576;
  u16* w_o_c    = wbf + 1835008;
  u16* w_1      = wbf + 2097152;
  u16* w_2      = wbf + 3145728;
  u16* hbuf     = wbf + 4194304;
  u16* qkv      = hbuf + 4194304;
  u16* kvc      = qkv + 4194304;
  u16* attnO    = qkv + 12582912;
  u16* hp       = attnO + 4194304;
  u16* ffnmid   = qkv;

  cvt6_kernel<<<4096, 256, 0, stream>>>(Wqkv_s, Wo_s, Wqkv_c, Wo_c, W1, W2,
                                        w_qkv_s, w_o_s, w_qkv_c, w_o_c, w_1, w_2);

  // self-attention block
  ln_kernel<<<2048, 256, 0, stream>>>(rna, g0, be0, hbuf, 8192);
  gemm_bt<0, 128><<<dim3(12, 64), 256, 0, stream>>>(hbuf, w_qkv_s, bqkv_s, nullptr, qkv, 8192, 1536, 512);
  vt_kernel<<<dim3(16, 8, 8), 256, 0, stream>>>(qkv + 1024, hbuf, 1536, 1024);
  attn_kernel<<<dim3(16, 8, 8), 256, 0, stream>>>(qkv, qkv + 512, hbuf, attnO, 1536, 1536, 1024);
  gemm_bt<2, 64><<<dim3(8, 64), 256, 0, stream>>>(attnO, w_o_s, bo_s, rna, out, 8192, 512, 512);

  // cross-attention block
  ln_kernel<<<2048, 256, 0, stream>>>(out, g11, be11, hbuf, 8192);
  ln_kernel<<<1024, 256, 0, stream>>>(prot, g12, be12, hp, 4096);
  gemm_bt<0, 64><<<dim3(8, 64), 256, 0, stream>>>(hbuf, w_qkv_c, bqkv_c, nullptr, qkv, 8192, 512, 512);
  gemm_bt<0, 64><<<dim3(16, 32), 256, 0, stream>>>(hp, w_qkv_c + 512 * 512, bqkv_c + 512, nullptr, kvc, 4096, 1024, 512);
  vt_kernel<<<dim3(8, 8, 8), 256, 0, stream>>>(kvc + 512, hp, 1024, 512);
  attn_kernel<<<dim3(16, 8, 8), 256, 0, stream>>>(qkv, kvc, hp, attnO, 512, 1024, 512);
  gemm_bt<2, 64><<<dim3(8, 64), 256, 0, stream>>>(attnO, w_o_c, bo_c, out, out, 8192, 512, 512);

  // FFN block
  ln_kernel<<<2048, 256, 0, stream>>>(out, g2, be2, hbuf, 8192);
  gemm_bt<1, 128><<<dim3(16, 64), 256, 0, stream>>>(hbuf, w_1, b1, nullptr, ffnmid, 8192, 2048, 512);
  gemm_bt<2, 64><<<dim3(8, 64), 256, 0, stream>>>(ffnmid, w_2, b2, out, out, 8192, 512, 2048);
}

// Round 5
// 216.479 us; speedup vs baseline: 1.5731x; 1.0264x over previous
//
#include <hip/hip_runtime.h>

typedef unsigned short u16;
typedef unsigned int u32;
typedef u16 u16x8 __attribute__((ext_vector_type(8)));
typedef u16 u16x4 __attribute__((ext_vector_type(4)));
typedef short bfx8 __attribute__((ext_vector_type(8)));
typedef float f32x4 __attribute__((ext_vector_type(4)));

#define AS1 __attribute__((address_space(1)))
#define AS3 __attribute__((address_space(3)))

__device__ __forceinline__ u16 f2bf(float f) {
  union { float f; u32 u; } c; c.f = f;
  u32 u = c.u;
  u += 0x7fffu + ((u >> 16) & 1u);
  return (u16)(u >> 16);
}

__device__ __forceinline__ u32 cvt_pk_bf16(float lo, float hi) {
  u32 r;
  asm("v_cvt_pk_bf16_f32 %0, %1, %2" : "=v"(r) : "v"(lo), "v"(hi));
  return r;
}

__device__ __forceinline__ float fexp2(float x) {
  float r;
  asm("v_exp_f32 %0, %1" : "=v"(r) : "v"(x));
  return r;
}

// ---------------- all-weights fp32 -> bf16 (merged) ----------------
__global__ __launch_bounds__(256) void cvt6_kernel(const float* __restrict__ a0, const float* __restrict__ a1,
                                                   const float* __restrict__ a2, const float* __restrict__ a3,
                                                   const float* __restrict__ a4, const float* __restrict__ a5,
                                                   u16* __restrict__ b0, u16* __restrict__ b1,
                                                   u16* __restrict__ b2, u16* __restrict__ b3,
                                                   u16* __restrict__ b4, u16* __restrict__ b5) {
  int i = blockIdx.x * 256 + threadIdx.x;
  const float* s; u16* d; int off;
  if      (i < 196608) { s = a0; d = b0; off = i; }
  else if (i < 262144) { s = a1; d = b1; off = i - 196608; }
  else if (i < 458752) { s = a2; d = b2; off = i - 262144; }
  else if (i < 524288) { s = a3; d = b3; off = i - 458752; }
  else if (i < 786432) { s = a4; d = b4; off = i - 524288; }
  else                 { s = a5; d = b5; off = i - 786432; }
  float4 v = ((const float4*)s)[off];
  u16x4 o;
  o[0] = f2bf(v.x); o[1] = f2bf(v.y); o[2] = f2bf(v.z); o[3] = f2bf(v.w);
  ((u16x4*)d)[off] = o;
}

// ---------------- LayerNorm (D=512), fp32 in -> bf16 out ----------------
__global__ __launch_bounds__(256) void ln_kernel(const float* __restrict__ x,
                                                 const float* __restrict__ g,
                                                 const float* __restrict__ be,
                                                 u16* __restrict__ out, int ntok) {
  int gw = (blockIdx.x * 256 + threadIdx.x) >> 6;
  int lane = threadIdx.x & 63;
  if (gw >= ntok) return;
  const float4* row = (const float4*)(x + (size_t)gw * 512);
  float4 a = row[2 * lane], b = row[2 * lane + 1];
  float s = a.x + a.y + a.z + a.w + b.x + b.y + b.z + b.w;
  float q = a.x*a.x + a.y*a.y + a.z*a.z + a.w*a.w + b.x*b.x + b.y*b.y + b.z*b.z + b.w*b.w;
#pragma unroll
  for (int m = 1; m < 64; m <<= 1) { s += __shfl_xor(s, m); q += __shfl_xor(q, m); }
  float mean = s * (1.f / 512.f);
  float var = q * (1.f / 512.f) - mean * mean;
  float rs = rsqrtf(var + 1e-5f);
  const float4* g4 = (const float4*)g;
  const float4* b4 = (const float4*)be;
  float4 ga = g4[2 * lane], gb = g4[2 * lane + 1];
  float4 ba = b4[2 * lane], bb = b4[2 * lane + 1];
  u16x8 o;
  o[0] = f2bf((a.x - mean) * rs * ga.x + ba.x);
  o[1] = f2bf((a.y - mean) * rs * ga.y + ba.y);
  o[2] = f2bf((a.z - mean) * rs * ga.z + ba.z);
  o[3] = f2bf((a.w - mean) * rs * ga.w + ba.w);
  o[4] = f2bf((b.x - mean) * rs * gb.x + bb.x);
  o[5] = f2bf((b.y - mean) * rs * gb.y + bb.y);
  o[6] = f2bf((b.z - mean) * rs * gb.z + bb.z);
  o[7] = f2bf((b.w - mean) * rs * gb.w + bb.w);
  ((u16x8*)(out + (size_t)gw * 512))[lane] = o;
}

// ---------------- V transpose: V(s,b,h,d) -> Vt[(b*8+h)*64+d][s] ----------------
__global__ __launch_bounds__(256) void vt_kernel(const u16* __restrict__ vB, u16* __restrict__ vt,
                                                 int stride, int S) {
  __shared__ u16 lt[64 * 68];
  const int t = threadIdx.x;
  const int b = blockIdx.y, h = blockIdx.z;
  const int sr = t >> 3, dc = (t & 7) * 8;
#pragma unroll
  for (int p = 0; p < 2; ++p) {
    int s = blockIdx.x * 64 + sr + p * 32;
    u16x8 v = *(const u16x8*)(vB + (size_t)(s * 8 + b) * stride + h * 64 + dc);
    u16x4 lo, hi;
    lo[0]=v[0]; lo[1]=v[1]; lo[2]=v[2]; lo[3]=v[3];
    hi[0]=v[4]; hi[1]=v[5]; hi[2]=v[6]; hi[3]=v[7];
    *(u16x4*)&lt[(sr + p * 32) * 68 + dc] = lo;
    *(u16x4*)&lt[(sr + p * 32) * 68 + dc + 4] = hi;
  }
  __syncthreads();
#pragma unroll
  for (int p = 0; p < 2; ++p) {
    int d = sr + p * 32;
    u16x8 o;
#pragma unroll
    for (int e = 0; e < 8; ++e) o[e] = lt[(dc + e) * 68 + d];
    *(u16x8*)(vt + ((size_t)(b * 8 + h) * 64 + d) * S + blockIdx.x * 64 + dc) = o;
  }
}

// ---------------- GEMM: C(N,M) = A(N,K)bf16 @ W(M,K)bf16^T + bias ----------------
template <int EPI, int BN>
__global__ __launch_bounds__(256) void gemm_bt(const u16* __restrict__ A,
                                               const u16* __restrict__ Bw,
                                               const float* __restrict__ bias,
                                               const float* __restrict__ res,
                                               void* __restrict__ Cout,
                                               int N, int M, int K) {
  constexpr int WC = BN / 64;
  constexpr int WR = 4 / WC;
  constexpr int RPW = 128 / WR;
  constexpr int IM = RPW / 16;
  __shared__ __align__(16) u16 lA[128 * 64];
  __shared__ __align__(16) u16 lB[BN * 64];
  const int tid = threadIdx.x;
  const int lane = tid & 63, w = tid >> 6;
  const int wr = w / WC, wc = w % WC;
  const int nwg = gridDim.x * gridDim.y;
  const int id = blockIdx.y * gridDim.x + blockIdx.x;
  const int swz = (id & 7) * (nwg >> 3) + (id >> 3);
  const int bn = (swz / gridDim.x) * 128;
  const int bm = (swz % gridDim.x) * BN;
  const int r15 = lane & 15, kg = lane >> 4;
  const int xr = (r15 & 7) << 4;

  f32x4 acc[IM][4] = {};

  const int lrw = lane >> 3;
  const int lcl = (((lane & 7) * 8) ^ (lrw * 8));

  for (int k0 = 0; k0 < K; k0 += 64) {
    const u16* gA = A + (size_t)bn * K + k0;
    const u16* gB = Bw + (size_t)bm * K + k0;
#pragma unroll
    for (int i = 0; i < 4; ++i) {
      int rbase = i * 32 + w * 8;
      __builtin_amdgcn_global_load_lds((AS1 u32*)(gA + (size_t)(rbase + lrw) * K + lcl),
                                       (AS3 u32*)&lA[rbase * 64], 16, 0, 0);
    }
#pragma unroll
    for (int i = 0; i < BN / 32; ++i) {
      int rbase = i * 32 + w * 8;
      __builtin_amdgcn_global_load_lds((AS1 u32*)(gB + (size_t)(rbase + lrw) * K + lcl),
                                       (AS3 u32*)&lB[rbase * 64], 16, 0, 0);
    }
    __syncthreads();
    const char* Ac = (const char*)lA;
    const char* Bc = (const char*)lB;
#pragma unroll
    for (int kk = 0; kk < 64; kk += 32) {
      bfx8 a[IM], b[4];
#pragma unroll
      for (int i = 0; i < IM; ++i)
        a[i] = *(const bfx8*)(Ac + (wr * RPW + i * 16 + r15) * 128 + ((kk * 2 + kg * 16) ^ xr));
#pragma unroll
      for (int j = 0; j < 4; ++j)
        b[j] = *(const bfx8*)(Bc + (wc * 64 + j * 16 + r15) * 128 + ((kk * 2 + kg * 16) ^ xr));
#pragma unroll
      for (int i = 0; i < IM; ++i)
#pragma unroll
        for (int j = 0; j < 4; ++j)
          acc[i][j] = __builtin_amdgcn_mfma_f32_16x16x32_bf16(a[i], b[j], acc[i][j], 0, 0, 0);
    }
    __syncthreads();
  }

#pragma unroll
  for (int i = 0; i < IM; ++i) {
#pragma unroll
    for (int j = 0; j < 4; ++j) {
      int col = bm + wc * 64 + j * 16 + r15;
      float bv = bias[col];
#pragma unroll
      for (int r = 0; r < 4; ++r) {
        int row = bn + wr * RPW + i * 16 + kg * 4 + r;
        float v = acc[i][j][r] + bv;
        if (EPI == 1) v = fmaxf(v, 0.f);
        if (EPI == 2) {
          ((float*)Cout)[(size_t)row * M + col] = res[(size_t)row * M + col] + v;
        } else {
          ((u16*)Cout)[(size_t)row * M + col] = f2bf(v);
        }
      }
    }
  }
}

// ---------------- flash attention v3: 8 waves, counted-vmcnt 2-deep pipeline ----------------
// Grid: 512 blocks 1-D. sid -> h=sid&7, b=(sid>>3)&7, qt=sid>>6 (XCD-coherent:
// all 8 q-tiles of one (b,h) land on one XCD -> K/V L2-resident).
// Per block: 128 q-rows (16/wave). K-tile 64, double-buffered, prefetch depth 2,
// raw s_barrier + counted s_waitcnt vmcnt (never 0 until last tile).
__global__ __launch_bounds__(512, 6) void attn_kernel(const u16* __restrict__ qB,
                                                      const u16* __restrict__ kB,
                                                      const u16* __restrict__ vtB,
                                                      u16* __restrict__ oB,
                                                      int qStride, int kvStride, int Sk) {
  __shared__ __align__(16) u16 lK[2][64 * 64];
  __shared__ __align__(16) u16 lVt[2][64 * 64];
  __shared__ __align__(16) u16 lP[8][16 * 64];
  const int tid = threadIdx.x, lane = tid & 63, w = tid >> 6;
  const int sid = blockIdx.x;
  const int h = sid & 7, b = (sid >> 3) & 7, qt = sid >> 6;
  const int r15 = lane & 15, kg = lane >> 4;
  const int srow = lane >> 3;
  const int sxcol = ((lane & 7) * 8) ^ (srow * 8);

  const int qs = qt * 128 + w * 16 + r15;
  const u16* qrow = qB + (size_t)(qs * 8 + b) * qStride + h * 64;
  bfx8 qf0 = *(const bfx8*)(qrow + kg * 8);
  bfx8 qf1 = *(const bfx8*)(qrow + 32 + kg * 8);

  const u16* vbase = vtB + ((size_t)(b * 8 + h) * 64) * Sk;
  const u16* kp0 = kB + ((size_t)(w * 8 + srow) * 8 + b) * kvStride + h * 64 + sxcol;
  const size_t kAdv = (size_t)64 * 8 * kvStride;
  const u16* vp0 = vbase + (size_t)(w * 8 + srow) * Sk + sxcol;

#define STAGE(buf, tt) do {                                                           \
    __builtin_amdgcn_global_load_lds((AS1 u32*)(kp0 + (size_t)(tt) * kAdv),           \
                                     (AS3 u32*)&lK[buf][(w * 8) * 64], 16, 0, 0);     \
    __builtin_amdgcn_global_load_lds((AS1 u32*)(vp0 + (size_t)(tt) * 64),             \
                                     (AS3 u32*)&lVt[buf][(w * 8) * 64], 16, 0, 0);    \
  } while (0)

  const int nt = Sk / 64;
  STAGE(0, 0);
  STAGE(1, 1);

  f32x4 oacc[4] = {};
  float mrow = -1e30f, lsum = 0.f;
  const float C2 = 0.125f * 1.44269504088896340736f;
  const int xr = (r15 & 7) << 4;
  char* myP = (char*)lP[w];

  for (int t = 0; t < nt; ++t) {
    int cur = t & 1;
    // wait for tile t's 2 loads (keep future tiles' loads in flight)
    if (t < nt - 1) { asm volatile("s_waitcnt vmcnt(2)" ::: "memory"); }
    else            { asm volatile("s_waitcnt vmcnt(0)" ::: "memory"); }
    __builtin_amdgcn_sched_barrier(0);
    __builtin_amdgcn_s_barrier();
    __builtin_amdgcn_sched_barrier(0);

    const char* Kc = (const char*)lK[cur];
    f32x4 st[4] = {};
    __builtin_amdgcn_s_setprio(1);
#pragma unroll
    for (int j = 0; j < 4; ++j) {
      const char* kp = Kc + (j * 16 + r15) * 128;
      bfx8 kf0 = *(const bfx8*)(kp + ((kg * 16) ^ xr));
      bfx8 kf1 = *(const bfx8*)(kp + ((64 + kg * 16) ^ xr));
      st[j] = __builtin_amdgcn_mfma_f32_16x16x32_bf16(kf0, qf0, st[j], 0, 0, 0);
      st[j] = __builtin_amdgcn_mfma_f32_16x16x32_bf16(kf1, qf1, st[j], 0, 0, 0);
    }
    __builtin_amdgcn_s_setprio(0);

    float m0 = fmaxf(fmaxf(fmaxf(st[0][0], st[0][1]), fmaxf(st[0][2], st[0][3])),
                     fmaxf(fmaxf(st[1][0], st[1][1]), fmaxf(st[1][2], st[1][3])));
    float m1 = fmaxf(fmaxf(fmaxf(st[2][0], st[2][1]), fmaxf(st[2][2], st[2][3])),
                     fmaxf(fmaxf(st[3][0], st[3][1]), fmaxf(st[3][2], st[3][3])));
    m0 = fmaxf(m0, m1);
    m0 = fmaxf(m0, __shfl_xor(m0, 16));
    m0 = fmaxf(m0, __shfl_xor(m0, 32));

    float mn = fmaxf(mrow, m0);
    float corr = fexp2((mrow - mn) * C2);
    mrow = mn;
    float bc = -mn * C2;

    float p[4][4];
#pragma unroll
    for (int j = 0; j < 4; ++j)
#pragma unroll
      for (int r = 0; r < 4; ++r)
        p[j][r] = fexp2(fmaf(st[j][r], C2, bc));

    float ps = ((p[0][0] + p[0][1]) + (p[0][2] + p[0][3]))
             + ((p[1][0] + p[1][1]) + (p[1][2] + p[1][3]))
             + ((p[2][0] + p[2][1]) + (p[2][2] + p[2][3]))
             + ((p[3][0] + p[3][1]) + (p[3][2] + p[3][3]));
    ps += __shfl_xor(ps, 16);
    ps += __shfl_xor(ps, 32);
    lsum = lsum * corr + ps;
#pragma unroll
    for (int jd = 0; jd < 4; ++jd)
#pragma unroll
      for (int r = 0; r < 4; ++r) oacc[jd][r] *= corr;

#pragma unroll
    for (int j = 0; j < 4; ++j)
#pragma unroll
      for (int h2 = 0; h2 < 2; ++h2) {
        u32 pk = cvt_pk_bf16(p[j][2 * h2], p[j][2 * h2 + 1]);
        int k0b = (j * 16 + kg * 4 + 2 * h2) * 2;
        *(u32*)(myP + r15 * 128 + (k0b ^ xr)) = pk;
      }

    const char* Vc = (const char*)lVt[cur];
    __builtin_amdgcn_s_setprio(1);
#pragma unroll
    for (int s2 = 0; s2 < 2; ++s2) {
      bfx8 ptf = *(const bfx8*)(myP + r15 * 128 + ((s2 * 64 + kg * 16) ^ xr));
#pragma unroll
      for (int jd = 0; jd < 4; ++jd) {
        const char* vp = Vc + (jd * 16 + r15) * 128;
        bfx8 vf = *(const bfx8*)(vp + ((s2 * 64 + kg * 16) ^ xr));
        oacc[jd] = __builtin_amdgcn_mfma_f32_16x16x32_bf16(vf, ptf, oacc[jd], 0, 0, 0);
      }
    }
    __builtin_amdgcn_s_setprio(0);

    __builtin_amdgcn_sched_barrier(0);
    __builtin_amdgcn_s_barrier();   // all waves done reading buf[cur]
    __builtin_amdgcn_sched_barrier(0);
    if (t + 2 < nt) STAGE(cur, t + 2);
  }
#undef STAGE

  float inv = 1.f / lsum;
  const int s = qt * 128 + w * 16 + r15;
  u16* orow = oB + (size_t)(s * 8 + b) * 512 + h * 64;
#pragma unroll
  for (int jd = 0; jd < 4; ++jd) {
    u32 p0 = cvt_pk_bf16(oacc[jd][0] * inv, oacc[jd][1] * inv);
    u32 p1 = cvt_pk_bf16(oacc[jd][2] * inv, oacc[jd][3] * inv);
    *(u32*)(orow + jd * 16 + kg * 4) = p0;
    *(u32*)(orow + jd * 16 + kg * 4 + 2) = p1;
  }
}

extern "C" void kernel_launch(void* const* d_in, const int* in_sizes, int n_in,
                              void* d_out, int out_size, void* d_ws, size_t ws_size,
                              hipStream_t stream) {
  const float* rna    = (const float*)d_in[0];
  const float* prot   = (const float*)d_in[1];
  const float* Wqkv_s = (const float*)d_in[2];
  const float* bqkv_s = (const float*)d_in[3];
  const float* Wo_s   = (const float*)d_in[4];
  const float* bo_s   = (const float*)d_in[5];
  const float* Wqkv_c = (const float*)d_in[6];
  const float* bqkv_c = (const float*)d_in[7];
  const float* Wo_c   = (const float*)d_in[8];
  const float* bo_c   = (const float*)d_in[9];
  const float* W1     = (const float*)d_in[10];
  const float* b1     = (const float*)d_in[11];
  const float* W2     = (const float*)d_in[12];
  const float* b2     = (const float*)d_in[13];
  const float* g0  = (const float*)d_in[14];
  const float* be0 = (const float*)d_in[15];
  const float* g11 = (const float*)d_in[16];
  const float* be11= (const float*)d_in[17];
  const float* g12 = (const float*)d_in[18];
  const float* be12= (const float*)d_in[19];
  const float* g2  = (const float*)d_in[20];
  const float* be2 = (const float*)d_in[21];
  float* out = (float*)d_out;

  u16* wbf      = (u16*)d_ws;
  u16* w_qkv_s  = wbf;
  u16* w_o_s    = wbf + 786432;
  u16* w_qkv_c  = wbf + 1048576;
  u16* w_o_c    = wbf + 1835008;
  u16* w_1      = wbf + 2097152;
  u16* w_2      = wbf + 3145728;
  u16* hbuf     = wbf + 4194304;
  u16* qkv      = hbuf + 4194304;
  u16* kvc      = qkv + 4194304;
  u16* attnO    = qkv + 12582912;
  u16* hp       = attnO + 4194304;
  u16* ffnmid   = qkv;

  cvt6_kernel<<<4096, 256, 0, stream>>>(Wqkv_s, Wo_s, Wqkv_c, Wo_c, W1, W2,
                                        w_qkv_s, w_o_s, w_qkv_c, w_o_c, w_1, w_2);

  // self-attention block
  ln_kernel<<<2048, 256, 0, stream>>>(rna, g0, be0, hbuf, 8192);
  gemm_bt<0, 128><<<dim3(12, 64), 256, 0, stream>>>(hbuf, w_qkv_s, bqkv_s, nullptr, qkv, 8192, 1536, 512);
  vt_kernel<<<dim3(16, 8, 8), 256, 0, stream>>>(qkv + 1024, hbuf, 1536, 1024);
  attn_kernel<<<512, 512, 0, stream>>>(qkv, qkv + 512, hbuf, attnO, 1536, 1536, 1024);
  gemm_bt<2, 64><<<dim3(8, 64), 256, 0, stream>>>(attnO, w_o_s, bo_s, rna, out, 8192, 512, 512);

  // cross-attention block
  ln_kernel<<<2048, 256, 0, stream>>>(out, g11, be11, hbuf, 8192);
  ln_kernel<<<1024, 256, 0, stream>>>(prot, g12, be12, hp, 4096);
  gemm_bt<0, 64><<<dim3(8, 64), 256, 0, stream>>>(hbuf, w_qkv_c, bqkv_c, nullptr, qkv, 8192, 512, 512);
  gemm_bt<0, 64><<<dim3(16, 32), 256, 0, stream>>>(hp, w_qkv_c + 512 * 512, bqkv_c + 512, nullptr, kvc, 4096, 1024, 512);
  vt_kernel<<<dim3(8, 8, 8), 256, 0, stream>>>(kvc + 512, hp, 1024, 512);
  attn_kernel<<<512, 512, 0, stream>>>(qkv, kvc, hp, attnO, 512, 1024, 512);
  gemm_bt<2, 64><<<dim3(8, 64), 256, 0, stream>>>(attnO, w_o_c, bo_c, out, out, 8192, 512, 512);

  // FFN block
  ln_kernel<<<2048, 256, 0, stream>>>(out, g2, be2, hbuf, 8192);
  gemm_bt<1, 128><<<dim3(16, 64), 256, 0, stream>>>(hbuf, w_1, b1, nullptr, ffnmid, 8192, 2048, 512);
  gemm_bt<2, 64><<<dim3(8, 64), 256, 0, stream>>>(ffnmid, w_2, b2, out, out, 8192, 512, 2048);
}

// Round 6
// 213.698 us; speedup vs baseline: 1.5936x; 1.0130x over previous
//
#include <hip/hip_runtime.h>

typedef unsigned short u16;
typedef unsigned int u32;
typedef u16 u16x8 __attribute__((ext_vector_type(8)));
typedef u16 u16x4 __attribute__((ext_vector_type(4)));
typedef short bfx8 __attribute__((ext_vector_type(8)));
typedef float f32x4 __attribute__((ext_vector_type(4)));

#define AS1 __attribute__((address_space(1)))
#define AS3 __attribute__((address_space(3)))

__device__ __forceinline__ u16 f2bf(float f) {
  union { float f; u32 u; } c; c.f = f;
  u32 u = c.u;
  u += 0x7fffu + ((u >> 16) & 1u);
  return (u16)(u >> 16);
}

__device__ __forceinline__ u32 cvt_pk_bf16(float lo, float hi) {
  u32 r;
  asm("v_cvt_pk_bf16_f32 %0, %1, %2" : "=v"(r) : "v"(lo), "v"(hi));
  return r;
}

__device__ __forceinline__ float fexp2(float x) {
  float r;
  asm("v_exp_f32 %0, %1" : "=v"(r) : "v"(x));
  return r;
}

// ---------------- all-weights fp32 -> bf16 (merged) ----------------
__global__ __launch_bounds__(256) void cvt6_kernel(const float* __restrict__ a0, const float* __restrict__ a1,
                                                   const float* __restrict__ a2, const float* __restrict__ a3,
                                                   const float* __restrict__ a4, const float* __restrict__ a5,
                                                   u16* __restrict__ b0, u16* __restrict__ b1,
                                                   u16* __restrict__ b2, u16* __restrict__ b3,
                                                   u16* __restrict__ b4, u16* __restrict__ b5) {
  int i = blockIdx.x * 256 + threadIdx.x;
  const float* s; u16* d; int off;
  if      (i < 196608) { s = a0; d = b0; off = i; }
  else if (i < 262144) { s = a1; d = b1; off = i - 196608; }
  else if (i < 458752) { s = a2; d = b2; off = i - 262144; }
  else if (i < 524288) { s = a3; d = b3; off = i - 458752; }
  else if (i < 786432) { s = a4; d = b4; off = i - 524288; }
  else                 { s = a5; d = b5; off = i - 786432; }
  float4 v = ((const float4*)s)[off];
  u16x4 o;
  o[0] = f2bf(v.x); o[1] = f2bf(v.y); o[2] = f2bf(v.z); o[3] = f2bf(v.w);
  ((u16x4*)d)[off] = o;
}

// ---------------- LayerNorm (D=512), fp32 in -> bf16 out ----------------
__global__ __launch_bounds__(256) void ln_kernel(const float* __restrict__ x,
                                                 const float* __restrict__ g,
                                                 const float* __restrict__ be,
                                                 u16* __restrict__ out, int ntok) {
  int gw = (blockIdx.x * 256 + threadIdx.x) >> 6;
  int lane = threadIdx.x & 63;
  if (gw >= ntok) return;
  const float4* row = (const float4*)(x + (size_t)gw * 512);
  float4 a = row[2 * lane], b = row[2 * lane + 1];
  float s = a.x + a.y + a.z + a.w + b.x + b.y + b.z + b.w;
  float q = a.x*a.x + a.y*a.y + a.z*a.z + a.w*a.w + b.x*b.x + b.y*b.y + b.z*b.z + b.w*b.w;
#pragma unroll
  for (int m = 1; m < 64; m <<= 1) { s += __shfl_xor(s, m); q += __shfl_xor(q, m); }
  float mean = s * (1.f / 512.f);
  float var = q * (1.f / 512.f) - mean * mean;
  float rs = rsqrtf(var + 1e-5f);
  const float4* g4 = (const float4*)g;
  const float4* b4 = (const float4*)be;
  float4 ga = g4[2 * lane], gb = g4[2 * lane + 1];
  float4 ba = b4[2 * lane], bb = b4[2 * lane + 1];
  u16x8 o;
  o[0] = f2bf((a.x - mean) * rs * ga.x + ba.x);
  o[1] = f2bf((a.y - mean) * rs * ga.y + ba.y);
  o[2] = f2bf((a.z - mean) * rs * ga.z + ba.z);
  o[3] = f2bf((a.w - mean) * rs * ga.w + ba.w);
  o[4] = f2bf((b.x - mean) * rs * gb.x + bb.x);
  o[5] = f2bf((b.y - mean) * rs * gb.y + bb.y);
  o[6] = f2bf((b.z - mean) * rs * gb.z + bb.z);
  o[7] = f2bf((b.w - mean) * rs * gb.w + bb.w);
  ((u16x8*)(out + (size_t)gw * 512))[lane] = o;
}

// ---------------- V transpose: V(s,b,h,d) -> Vt[(b*8+h)*64+d][s] ----------------
__global__ __launch_bounds__(256) void vt_kernel(const u16* __restrict__ vB, u16* __restrict__ vt,
                                                 int stride, int S) {
  __shared__ u16 lt[64 * 68];
  const int t = threadIdx.x;
  const int b = blockIdx.y, h = blockIdx.z;
  const int sr = t >> 3, dc = (t & 7) * 8;
#pragma unroll
  for (int p = 0; p < 2; ++p) {
    int s = blockIdx.x * 64 + sr + p * 32;
    u16x8 v = *(const u16x8*)(vB + (size_t)(s * 8 + b) * stride + h * 64 + dc);
    u16x4 lo, hi;
    lo[0]=v[0]; lo[1]=v[1]; lo[2]=v[2]; lo[3]=v[3];
    hi[0]=v[4]; hi[1]=v[5]; hi[2]=v[6]; hi[3]=v[7];
    *(u16x4*)&lt[(sr + p * 32) * 68 + dc] = lo;
    *(u16x4*)&lt[(sr + p * 32) * 68 + dc + 4] = hi;
  }
  __syncthreads();
#pragma unroll
  for (int p = 0; p < 2; ++p) {
    int d = sr + p * 32;
    u16x8 o;
#pragma unroll
    for (int e = 0; e < 8; ++e) o[e] = lt[(dc + e) * 68 + d];
    *(u16x8*)(vt + ((size_t)(b * 8 + h) * 64 + d) * S + blockIdx.x * 64 + dc) = o;
  }
}

// ---------------- GEMM (128 x BN tile, 4 waves): C = A @ W^T + bias ----------------
template <int EPI, int BN>
__global__ __launch_bounds__(256) void gemm_bt(const u16* __restrict__ A,
                                               const u16* __restrict__ Bw,
                                               const float* __restrict__ bias,
                                               const float* __restrict__ res,
                                               void* __restrict__ Cout,
                                               int N, int M, int K) {
  constexpr int WC = BN / 64;
  constexpr int WR = 4 / WC;
  constexpr int RPW = 128 / WR;
  constexpr int IM = RPW / 16;
  __shared__ __align__(16) u16 lA[128 * 64];
  __shared__ __align__(16) u16 lB[BN * 64];
  const int tid = threadIdx.x;
  const int lane = tid & 63, w = tid >> 6;
  const int wr = w / WC, wc = w % WC;
  const int nwg = gridDim.x * gridDim.y;
  const int id = blockIdx.y * gridDim.x + blockIdx.x;
  const int swz = (id & 7) * (nwg >> 3) + (id >> 3);
  const int bn = (swz / gridDim.x) * 128;
  const int bm = (swz % gridDim.x) * BN;
  const int r15 = lane & 15, kg = lane >> 4;
  const int xr = (r15 & 7) << 4;

  f32x4 acc[IM][4] = {};

  const int lrw = lane >> 3;
  const int lcl = (((lane & 7) * 8) ^ (lrw * 8));

  for (int k0 = 0; k0 < K; k0 += 64) {
    const u16* gA = A + (size_t)bn * K + k0;
    const u16* gB = Bw + (size_t)bm * K + k0;
#pragma unroll
    for (int i = 0; i < 4; ++i) {
      int rbase = i * 32 + w * 8;
      __builtin_amdgcn_global_load_lds((AS1 u32*)(gA + (size_t)(rbase + lrw) * K + lcl),
                                       (AS3 u32*)&lA[rbase * 64], 16, 0, 0);
    }
#pragma unroll
    for (int i = 0; i < BN / 32; ++i) {
      int rbase = i * 32 + w * 8;
      __builtin_amdgcn_global_load_lds((AS1 u32*)(gB + (size_t)(rbase + lrw) * K + lcl),
                                       (AS3 u32*)&lB[rbase * 64], 16, 0, 0);
    }
    __syncthreads();
    const char* Ac = (const char*)lA;
    const char* Bc = (const char*)lB;
#pragma unroll
    for (int kk = 0; kk < 64; kk += 32) {
      bfx8 a[IM], b[4];
#pragma unroll
      for (int i = 0; i < IM; ++i)
        a[i] = *(const bfx8*)(Ac + (wr * RPW + i * 16 + r15) * 128 + ((kk * 2 + kg * 16) ^ xr));
#pragma unroll
      for (int j = 0; j < 4; ++j)
        b[j] = *(const bfx8*)(Bc + (wc * 64 + j * 16 + r15) * 128 + ((kk * 2 + kg * 16) ^ xr));
#pragma unroll
      for (int i = 0; i < IM; ++i)
#pragma unroll
        for (int j = 0; j < 4; ++j)
          acc[i][j] = __builtin_amdgcn_mfma_f32_16x16x32_bf16(a[i], b[j], acc[i][j], 0, 0, 0);
    }
    __syncthreads();
  }

#pragma unroll
  for (int i = 0; i < IM; ++i) {
#pragma unroll
    for (int j = 0; j < 4; ++j) {
      int col = bm + wc * 64 + j * 16 + r15;
      float bv = bias[col];
#pragma unroll
      for (int r = 0; r < 4; ++r) {
        int row = bn + wr * RPW + i * 16 + kg * 4 + r;
        float v = acc[i][j][r] + bv;
        if (EPI == 1) v = fmaxf(v, 0.f);
        if (EPI == 2) {
          ((float*)Cout)[(size_t)row * M + col] = res[(size_t)row * M + col] + v;
        } else {
          ((u16*)Cout)[(size_t)row * M + col] = f2bf(v);
        }
      }
    }
  }
}

// ---------------- big GEMM: 256x256 tile, 8 waves, 2-phase counted-vmcnt ----------------
// Wave tile 128x64 (acc 8x4 frags -> 64 MFMA : 24 ds_read per K-step).
// LDS double-buffered 128 KB (1 block/CU); next tile's 8 loads stay in flight
// through the whole compute phase (vmcnt(8), drain only on last tile).
template <int EPI>
__global__ __launch_bounds__(512, 2) void gemm_big(const u16* __restrict__ A,
                                                   const u16* __restrict__ Bw,
                                                   const float* __restrict__ bias,
                                                   void* __restrict__ Cout,
                                                   int N, int M, int K) {
  __shared__ __align__(16) u16 lA[2][256 * 64];
  __shared__ __align__(16) u16 lB[2][256 * 64];
  const int tid = threadIdx.x;
  const int lane = tid & 63, w = tid >> 6;
  const int wr = w >> 2, wc = w & 3;
  const int nwg = gridDim.x * gridDim.y;
  const int id = blockIdx.y * gridDim.x + blockIdx.x;
  const int swz = (id & 7) * (nwg >> 3) + (id >> 3);
  const int bn = (swz / gridDim.x) * 256;
  const int bm = (swz % gridDim.x) * 256;
  const int r15 = lane & 15, kg = lane >> 4;
  const int xr = (r15 & 7) << 4;

  f32x4 acc[8][4] = {};

  const int lrw = tid >> 3;                                 // 0..63
  const int lcl = ((tid & 7) * 8) ^ ((lrw & 7) * 8);        // swizzled src col (u16)
  const u16* gA = A + (size_t)(bn + lrw) * K + lcl;
  const u16* gB = Bw + (size_t)(bm + lrw) * K + lcl;
  const int ldsbase = (w * 8) * 64;                         // wave-uniform dest base

#define STAGEB(buf, t) do {                                                              \
    _Pragma("unroll")                                                                    \
    for (int i_ = 0; i_ < 4; ++i_) {                                                     \
      __builtin_amdgcn_global_load_lds((AS1 u32*)(gA + (size_t)(i_ * 64) * K + (t) * 64),\
                                       (AS3 u32*)&lA[buf][i_ * 4096 + ldsbase], 16, 0, 0);\
      __builtin_amdgcn_global_load_lds((AS1 u32*)(gB + (size_t)(i_ * 64) * K + (t) * 64),\
                                       (AS3 u32*)&lB[buf][i_ * 4096 + ldsbase], 16, 0, 0);\
    }                                                                                    \
  } while (0)

  const int nk = K >> 6;
  STAGEB(0, 0);
  for (int t = 0; t < nk; ++t) {
    const int cur = t & 1;
    if (t + 1 < nk) {
      STAGEB(cur ^ 1, t + 1);
      asm volatile("s_waitcnt vmcnt(8)" ::: "memory");
    } else {
      asm volatile("s_waitcnt vmcnt(0)" ::: "memory");
    }
    __builtin_amdgcn_sched_barrier(0);
    __builtin_amdgcn_s_barrier();
    __builtin_amdgcn_sched_barrier(0);

    const char* Ac = (const char*)lA[cur];
    const char* Bc = (const char*)lB[cur];
    __builtin_amdgcn_s_setprio(1);
#pragma unroll
    for (int kk = 0; kk < 2; ++kk) {
      bfx8 a[8], b[4];
#pragma unroll
      for (int i = 0; i < 8; ++i)
        a[i] = *(const bfx8*)(Ac + (wr * 128 + i * 16 + r15) * 128 + ((kk * 64 + kg * 16) ^ xr));
#pragma unroll
      for (int j = 0; j < 4; ++j)
        b[j] = *(const bfx8*)(Bc + (wc * 64 + j * 16 + r15) * 128 + ((kk * 64 + kg * 16) ^ xr));
#pragma unroll
      for (int i = 0; i < 8; ++i)
#pragma unroll
        for (int j = 0; j < 4; ++j)
          acc[i][j] = __builtin_amdgcn_mfma_f32_16x16x32_bf16(a[i], b[j], acc[i][j], 0, 0, 0);
    }
    __builtin_amdgcn_s_setprio(0);
    __builtin_amdgcn_sched_barrier(0);
    __builtin_amdgcn_s_barrier();   // all waves done with buf[cur] before re-stage
  }
#undef STAGEB

#pragma unroll
  for (int i = 0; i < 8; ++i) {
#pragma unroll
    for (int j = 0; j < 4; ++j) {
      int col = bm + wc * 64 + j * 16 + r15;
      float bv = bias[col];
#pragma unroll
      for (int r = 0; r < 4; ++r) {
        int row = bn + wr * 128 + i * 16 + kg * 4 + r;
        float v = acc[i][j][r] + bv;
        if (EPI == 1) v = fmaxf(v, 0.f);
        ((u16*)Cout)[(size_t)row * M + col] = f2bf(v);
      }
    }
  }
}

// ---------------- flash attention: 8 waves, counted-vmcnt 2-deep pipeline ----------------
__global__ __launch_bounds__(512, 6) void attn_kernel(const u16* __restrict__ qB,
                                                      const u16* __restrict__ kB,
                                                      const u16* __restrict__ vtB,
                                                      u16* __restrict__ oB,
                                                      int qStride, int kvStride, int Sk) {
  __shared__ __align__(16) u16 lK[2][64 * 64];
  __shared__ __align__(16) u16 lVt[2][64 * 64];
  __shared__ __align__(16) u16 lP[8][16 * 64];
  const int tid = threadIdx.x, lane = tid & 63, w = tid >> 6;
  const int sid = blockIdx.x;
  const int h = sid & 7, b = (sid >> 3) & 7, qt = sid >> 6;
  const int r15 = lane & 15, kg = lane >> 4;
  const int srow = lane >> 3;
  const int sxcol = ((lane & 7) * 8) ^ (srow * 8);

  const int qs = qt * 128 + w * 16 + r15;
  const u16* qrow = qB + (size_t)(qs * 8 + b) * qStride + h * 64;
  bfx8 qf0 = *(const bfx8*)(qrow + kg * 8);
  bfx8 qf1 = *(const bfx8*)(qrow + 32 + kg * 8);

  const u16* vbase = vtB + ((size_t)(b * 8 + h) * 64) * Sk;
  const u16* kp0 = kB + ((size_t)(w * 8 + srow) * 8 + b) * kvStride + h * 64 + sxcol;
  const size_t kAdv = (size_t)64 * 8 * kvStride;
  const u16* vp0 = vbase + (size_t)(w * 8 + srow) * Sk + sxcol;

#define STAGE(buf, tt) do {                                                           \
    __builtin_amdgcn_global_load_lds((AS1 u32*)(kp0 + (size_t)(tt) * kAdv),           \
                                     (AS3 u32*)&lK[buf][(w * 8) * 64], 16, 0, 0);     \
    __builtin_amdgcn_global_load_lds((AS1 u32*)(vp0 + (size_t)(tt) * 64),             \
                                     (AS3 u32*)&lVt[buf][(w * 8) * 64], 16, 0, 0);    \
  } while (0)

  const int nt = Sk / 64;
  STAGE(0, 0);
  STAGE(1, 1);

  f32x4 oacc[4] = {};
  float mrow = -1e30f, lsum = 0.f;
  const float C2 = 0.125f * 1.44269504088896340736f;
  const int xr = (r15 & 7) << 4;
  char* myP = (char*)lP[w];

  for (int t = 0; t < nt; ++t) {
    int cur = t & 1;
    if (t < nt - 1) { asm volatile("s_waitcnt vmcnt(2)" ::: "memory"); }
    else            { asm volatile("s_waitcnt vmcnt(0)" ::: "memory"); }
    __builtin_amdgcn_sched_barrier(0);
    __builtin_amdgcn_s_barrier();
    __builtin_amdgcn_sched_barrier(0);

    const char* Kc = (const char*)lK[cur];
    f32x4 st[4] = {};
    __builtin_amdgcn_s_setprio(1);
#pragma unroll
    for (int j = 0; j < 4; ++j) {
      const char* kp = Kc + (j * 16 + r15) * 128;
      bfx8 kf0 = *(const bfx8*)(kp + ((kg * 16) ^ xr));
      bfx8 kf1 = *(const bfx8*)(kp + ((64 + kg * 16) ^ xr));
      st[j] = __builtin_amdgcn_mfma_f32_16x16x32_bf16(kf0, qf0, st[j], 0, 0, 0);
      st[j] = __builtin_amdgcn_mfma_f32_16x16x32_bf16(kf1, qf1, st[j], 0, 0, 0);
    }
    __builtin_amdgcn_s_setprio(0);

    float m0 = fmaxf(fmaxf(fmaxf(st[0][0], st[0][1]), fmaxf(st[0][2], st[0][3])),
                     fmaxf(fmaxf(st[1][0], st[1][1]), fmaxf(st[1][2], st[1][3])));
    float m1 = fmaxf(fmaxf(fmaxf(st[2][0], st[2][1]), fmaxf(st[2][2], st[2][3])),
                     fmaxf(fmaxf(st[3][0], st[3][1]), fmaxf(st[3][2], st[3][3])));
    m0 = fmaxf(m0, m1);
    m0 = fmaxf(m0, __shfl_xor(m0, 16));
    m0 = fmaxf(m0, __shfl_xor(m0, 32));

    float mn = fmaxf(mrow, m0);
    float corr = fexp2((mrow - mn) * C2);
    mrow = mn;
    float bc = -mn * C2;

    float p[4][4];
#pragma unroll
    for (int j = 0; j < 4; ++j)
#pragma unroll
      for (int r = 0; r < 4; ++r)
        p[j][r] = fexp2(fmaf(st[j][r], C2, bc));

    float ps = ((p[0][0] + p[0][1]) + (p[0][2] + p[0][3]))
             + ((p[1][0] + p[1][1]) + (p[1][2] + p[1][3]))
             + ((p[2][0] + p[2][1]) + (p[2][2] + p[2][3]))
             + ((p[3][0] + p[3][1]) + (p[3][2] + p[3][3]));
    ps += __shfl_xor(ps, 16);
    ps += __shfl_xor(ps, 32);
    lsum = lsum * corr + ps;
#pragma unroll
    for (int jd = 0; jd < 4; ++jd)
#pragma unroll
      for (int r = 0; r < 4; ++r) oacc[jd][r] *= corr;

#pragma unroll
    for (int j = 0; j < 4; ++j)
#pragma unroll
      for (int h2 = 0; h2 < 2; ++h2) {
        u32 pk = cvt_pk_bf16(p[j][2 * h2], p[j][2 * h2 + 1]);
        int k0b = (j * 16 + kg * 4 + 2 * h2) * 2;
        *(u32*)(myP + r15 * 128 + (k0b ^ xr)) = pk;
      }

    const char* Vc = (const char*)lVt[cur];
    __builtin_amdgcn_s_setprio(1);
#pragma unroll
    for (int s2 = 0; s2 < 2; ++s2) {
      bfx8 ptf = *(const bfx8*)(myP + r15 * 128 + ((s2 * 64 + kg * 16) ^ xr));
#pragma unroll
      for (int jd = 0; jd < 4; ++jd) {
        const char* vp = Vc + (jd * 16 + r15) * 128;
        bfx8 vf = *(const bfx8*)(vp + ((s2 * 64 + kg * 16) ^ xr));
        oacc[jd] = __builtin_amdgcn_mfma_f32_16x16x32_bf16(vf, ptf, oacc[jd], 0, 0, 0);
      }
    }
    __builtin_amdgcn_s_setprio(0);

    __builtin_amdgcn_sched_barrier(0);
    __builtin_amdgcn_s_barrier();
    __builtin_amdgcn_sched_barrier(0);
    if (t + 2 < nt) STAGE(cur, t + 2);
  }
#undef STAGE

  float inv = 1.f / lsum;
  const int s = qt * 128 + w * 16 + r15;
  u16* orow = oB + (size_t)(s * 8 + b) * 512 + h * 64;
#pragma unroll
  for (int jd = 0; jd < 4; ++jd) {
    u32 p0 = cvt_pk_bf16(oacc[jd][0] * inv, oacc[jd][1] * inv);
    u32 p1 = cvt_pk_bf16(oacc[jd][2] * inv, oacc[jd][3] * inv);
    *(u32*)(orow + jd * 16 + kg * 4) = p0;
    *(u32*)(orow + jd * 16 + kg * 4 + 2) = p1;
  }
}

extern "C" void kernel_launch(void* const* d_in, const int* in_sizes, int n_in,
                              void* d_out, int out_size, void* d_ws, size_t ws_size,
                              hipStream_t stream) {
  const float* rna    = (const float*)d_in[0];
  const float* prot   = (const float*)d_in[1];
  const float* Wqkv_s = (const float*)d_in[2];
  const float* bqkv_s = (const float*)d_in[3];
  const float* Wo_s   = (const float*)d_in[4];
  const float* bo_s   = (const float*)d_in[5];
  const float* Wqkv_c = (const float*)d_in[6];
  const float* bqkv_c = (const float*)d_in[7];
  const float* Wo_c   = (const float*)d_in[8];
  const float* bo_c   = (const float*)d_in[9];
  const float* W1     = (const float*)d_in[10];
  const float* b1     = (const float*)d_in[11];
  const float* W2     = (const float*)d_in[12];
  const float* b2     = (const float*)d_in[13];
  const float* g0  = (const float*)d_in[14];
  const float* be0 = (const float*)d_in[15];
  const float* g11 = (const float*)d_in[16];
  const float* be11= (const float*)d_in[17];
  const float* g12 = (const float*)d_in[18];
  const float* be12= (const float*)d_in[19];
  const float* g2  = (const float*)d_in[20];
  const float* be2 = (const float*)d_in[21];
  float* out = (float*)d_out;

  u16* wbf      = (u16*)d_ws;
  u16* w_qkv_s  = wbf;
  u16* w_o_s    = wbf + 786432;
  u16* w_qkv_c  = wbf + 1048576;
  u16* w_o_c    = wbf + 1835008;
  u16* w_1      = wbf + 2097152;
  u16* w_2      = wbf + 3145728;
  u16* hbuf     = wbf + 4194304;
  u16* qkv      = hbuf + 4194304;
  u16* kvc      = qkv + 4194304;
  u16* attnO    = qkv + 12582912;
  u16* hp       = attnO + 4194304;
  u16* ffnmid   = qkv;

  cvt6_kernel<<<4096, 256, 0, stream>>>(Wqkv_s, Wo_s, Wqkv_c, Wo_c, W1, W2,
                                        w_qkv_s, w_o_s, w_qkv_c, w_o_c, w_1, w_2);

  // self-attention block
  ln_kernel<<<2048, 256, 0, stream>>>(rna, g0, be0, hbuf, 8192);
  gemm_big<0><<<dim3(6, 32), 512, 0, stream>>>(hbuf, w_qkv_s, bqkv_s, qkv, 8192, 1536, 512);
  vt_kernel<<<dim3(16, 8, 8), 256, 0, stream>>>(qkv + 1024, hbuf, 1536, 1024);
  attn_kernel<<<512, 512, 0, stream>>>(qkv, qkv + 512, hbuf, attnO, 1536, 1536, 1024);
  gemm_bt<2, 64><<<dim3(8, 64), 256, 0, stream>>>(attnO, w_o_s, bo_s, rna, out, 8192, 512, 512);

  // cross-attention block
  ln_kernel<<<2048, 256, 0, stream>>>(out, g11, be11, hbuf, 8192);
  ln_kernel<<<1024, 256, 0, stream>>>(prot, g12, be12, hp, 4096);
  gemm_bt<0, 64><<<dim3(8, 64), 256, 0, stream>>>(hbuf, w_qkv_c, bqkv_c, nullptr, qkv, 8192, 512, 512);
  gemm_bt<0, 64><<<dim3(16, 32), 256, 0, stream>>>(hp, w_qkv_c + 512 * 512, bqkv_c + 512, nullptr, kvc, 4096, 1024, 512);
  vt_kernel<<<dim3(8, 8, 8), 256, 0, stream>>>(kvc + 512, hp, 1024, 512);
  attn_kernel<<<512, 512, 0, stream>>>(qkv, kvc, hp, attnO, 512, 1024, 512);
  gemm_bt<2, 64><<<dim3(8, 64), 256, 0, stream>>>(attnO, w_o_c, bo_c, out, out, 8192, 512, 512);

  // FFN block
  ln_kernel<<<2048, 256, 0, stream>>>(out, g2, be2, hbuf, 8192);
  gemm_big<1><<<dim3(8, 32), 512, 0, stream>>>(hbuf, w_1, b1, ffnmid, 8192, 2048, 512);
  gemm_bt<2, 64><<<dim3(8, 64), 256, 0, stream>>>(ffnmid, w_2, b2, out, out, 8192, 512, 2048);
}